// Round 5
// baseline (286.907 us; speedup 1.0000x reference)
//
#include <hip/hip_runtime.h>
#include <stdint.h>

#define BN 16384
#define DD 1024
#define HH 256
#define EE 8
#define GB 1024  // gating blocks
#define GR 16    // rows per gating block

typedef __attribute__((ext_vector_type(8))) short short8;
typedef __attribute__((ext_vector_type(4))) float floatx4;

__device__ __forceinline__ unsigned short f2bf(float f) {
  union { float f; unsigned int i; } v; v.f = f;
  unsigned int x = v.i;
  x += 0x7fffu + ((x >> 16) & 1u);  // RTNE
  return (unsigned short)(x >> 16);
}
__device__ __forceinline__ unsigned int pack2(float a, float b) {
  return (unsigned int)f2bf(a) | ((unsigned int)f2bf(b) << 16);
}
__device__ __forceinline__ float bf2f(unsigned int u16) {
  union { unsigned int i; float f; } v; v.i = u16 << 16; return v.f;
}
// async 16B/lane global->LDS DMA; lds dst must be wave-uniform base (+lane*16 by HW)
__device__ __forceinline__ void async16(const unsigned short* g, unsigned short* l) {
  __builtin_amdgcn_global_load_lds(
      (const __attribute__((address_space(1))) void*)g,
      (__attribute__((address_space(3))) void*)l, 16, 0, 0);
}

// ---------------- gating: fp32 logits -> top2 -> rinfo + per-block histogram ----------------
// merged grouping: one list per expert (8 groups); a row contributes to both its experts' bins
// Also converts x -> bf16 xb on the fly. GB=1024 -> 4 blocks/CU (latency hiding).
// Reduce-scatter expert reduction: 15 shuffles/row instead of 48.
__global__ __launch_bounds__(256) void gating_kernel(
    const float* __restrict__ x,
    const float* __restrict__ gate_w,
    const float* __restrict__ gate_b,
    int* __restrict__ rinfo_e, float* __restrict__ rinfo_w,
    int* __restrict__ bhist,
    unsigned short* __restrict__ xb) {   // nullable
  __shared__ int hist[EE];
  int tid = threadIdx.x;
  if (tid < EE) hist[tid] = 0;
  __syncthreads();
  int lane = tid & 63, wv = tid >> 6;
  int p0 = lane & 1, p1 = (lane >> 1) & 1, p2 = (lane >> 2) & 1;
  float gb[EE];
#pragma unroll
  for (int e = 0; e < EE; e++) gb[e] = gate_b[e];
#pragma unroll 1
  for (int it = 0; it < GR / 4; it++) {
    int row = blockIdx.x * GR + it * 4 + wv;
    const float4* xr4 = (const float4*)(x + (size_t)row * DD);
    float acc[EE];
#pragma unroll
    for (int e = 0; e < EE; e++) acc[e] = 0.f;
#pragma unroll
    for (int i = 0; i < 4; i++) {
      int d4 = lane + i * 64;  // float4 index
      float4 xv = xr4[d4];
      if (xb) {
        uint2 st; st.x = pack2(xv.x, xv.y); st.y = pack2(xv.z, xv.w);
        *(uint2*)(xb + (size_t)row * DD + (size_t)d4 * 4) = st;
      }
      const float4* gp = (const float4*)gate_w + (size_t)d4 * 8;
      float xs[4] = {xv.x, xv.y, xv.z, xv.w};
#pragma unroll
      for (int j = 0; j < 4; j++) {
        float4 glo = gp[2 * j], ghi = gp[2 * j + 1];
        acc[0] += xs[j] * glo.x; acc[1] += xs[j] * glo.y;
        acc[2] += xs[j] * glo.z; acc[3] += xs[j] * glo.w;
        acc[4] += xs[j] * ghi.x; acc[5] += xs[j] * ghi.y;
        acc[6] += xs[j] * ghi.z; acc[7] += xs[j] * ghi.w;
      }
    }
    // reduce-scatter: halve live values 8->4->2->1 (4+2+1 shuffles),
    // then 3-stage butterfly across 8-lane groups. Lane ends holding the
    // full sum for expert e(lane) = ((lane&1)<<2) | (lane&2) | ((lane>>2)&1).
    float v4[4];
#pragma unroll
    for (int k = 0; k < 4; k++) {
      float send = p0 ? acc[k] : acc[k + 4];        // value the partner keeps
      float recv = __shfl_xor(send, 1, 64);
      v4[k] = (p0 ? acc[k + 4] : acc[k]) + recv;
    }
    float v2[2];
#pragma unroll
    for (int k = 0; k < 2; k++) {
      float send = p1 ? v4[k] : v4[k + 2];
      float recv = __shfl_xor(send, 2, 64);
      v2[k] = (p1 ? v4[k + 2] : v4[k]) + recv;
    }
    float v1;
    {
      float send = p2 ? v2[0] : v2[1];
      float recv = __shfl_xor(send, 4, 64);
      v1 = (p2 ? v2[1] : v2[0]) + recv;
    }
    v1 += __shfl_xor(v1, 8, 64);
    v1 += __shfl_xor(v1, 16, 64);
    v1 += __shfl_xor(v1, 32, 64);
    // gather logits (mapping is an involution: laneFor(e) uses same formula)
    float lg[EE];
#pragma unroll
    for (int e = 0; e < EE; e++) {
      int src = ((e & 1) << 2) | (e & 2) | ((e >> 2) & 1);
      lg[e] = __shfl(v1, src, 64) + gb[e];
    }
    if (lane == 0) {
      int i1 = 0;
      for (int e = 1; e < EE; e++) if (lg[e] > lg[i1]) i1 = e;
      int i2 = (i1 == 0) ? 1 : 0;
      for (int e = 0; e < EE; e++) if (e != i1 && lg[e] > lg[i2]) i2 = e;
      float wA = 1.f / (1.f + __expf(lg[i2] - lg[i1]));  // p1/(p1+p2), arg <= 0
      float wB = 1.f - wA;
      rinfo_e[row] = i1 | (i2 << 8);
      rinfo_w[row * 2 + 0] = wA;
      rinfo_w[row * 2 + 1] = wB;
      atomicAdd(&hist[i1], 1);      // LDS atomics only
      atomicAdd(&hist[i2], 1);
    }
  }
  __syncthreads();
  if (tid < EE) bhist[blockIdx.x * EE + tid] = hist[tid];
}

// ---------------- scan: totals, group offsets, per-block bases (deterministic) ----------------
__global__ __launch_bounds__(256) void scan_kernel(
    const int* __restrict__ bhist, int* __restrict__ cnt, int* __restrict__ bbase) {
  __shared__ int cs[32][EE];
  __shared__ int ofs[EE];
  int tid = threadIdx.x;
  int g = tid & 7, c = tid >> 3;   // 32 chunks of 32 blocks (GB=1024)
  int s = 0;
#pragma unroll 1
  for (int b = c * 32; b < c * 32 + 32; b++) s += bhist[b * EE + g];
  cs[c][g] = s;
  __syncthreads();
  if (tid == 0) {
    int run = 0;
    for (int gg = 0; gg < EE; gg++) {
      int tot = 0;
      for (int cc = 0; cc < 32; cc++) tot += cs[cc][gg];
      cnt[gg] = tot;
      cnt[32 + gg] = run;
      ofs[gg] = run;
      run += tot;
    }
  }
  __syncthreads();
  if (tid < EE) {
    int run = ofs[tid];
#pragma unroll 1
    for (int cc = 0; cc < 32; cc++) { int t = cs[cc][tid]; cs[cc][tid] = run; run += t; }
  }
  __syncthreads();
  int run = cs[c][g];
#pragma unroll 1
  for (int b = c * 32; b < c * 32 + 32; b++) {
    bbase[b * EE + g] = run;
    run += bhist[b * EE + g];
  }
}

// ---------------- scatter (also writes inverse map row -> (p0,p1)) ----------------
// NOTE: posmap may alias rinfo_w; reads of rinfo_w happen before posmap writes in-thread.
__global__ __launch_bounds__(64) void scatter_kernel(
    const int* __restrict__ rinfo_e, const float* rinfo_w,
    const int* __restrict__ bbase,
    int* __restrict__ rowidx, float* __restrict__ wgt, int* posmap) {
  __shared__ int curs[EE];
  int tid = threadIdx.x;
  if (tid < EE) curs[tid] = bbase[blockIdx.x * EE + tid];
  __syncthreads();
  if (tid < GR) {
    int row = blockIdx.x * GR + tid;
    int ee = rinfo_e[row];
    int e0 = ee & 255, e1 = (ee >> 8) & 255;
    float w0 = rinfo_w[row * 2 + 0];
    float w1 = rinfo_w[row * 2 + 1];
    int p0 = atomicAdd(&curs[e0], 1);
    rowidx[p0] = row; wgt[p0] = w0;
    int p1 = atomicAdd(&curs[e1], 1);
    rowidx[p1] = row; wgt[p1] = w1;
    posmap[row * 2 + 0] = p0;
    posmap[row * 2 + 1] = p1;
  }
}

// src fp32 [E][R][C] -> dst bf16 [E][C][R]
__global__ void transpose_kernel(const float* __restrict__ src,
                                 unsigned short* __restrict__ dst, int R, int C) {
  __shared__ float tbuf[32][33];
  int e = blockIdx.z;
  int c0 = blockIdx.x * 32, r0 = blockIdx.y * 32;
  int tx = threadIdx.x, ty = threadIdx.y;
  const float* s = src + (size_t)e * R * C;
  unsigned short* d = dst + (size_t)e * R * C;
  for (int yy = ty; yy < 32; yy += 8)
    tbuf[yy][tx] = s[(size_t)(r0 + yy) * C + c0 + tx];
  __syncthreads();
  for (int yy = ty; yy < 32; yy += 8)
    d[(size_t)(c0 + yy) * R + r0 + tx] = f2bf(tbuf[tx][yy]);
}

// ---------------- grouped GEMM1: h = gelu(Xg @ w1[e] + b1[e]) ----------------
// 128(M)x64(N) tile, grid (264,4) = 1056 blocks -> ~4 blocks/CU (16 waves/CU):
// latency hidden by cross-block TLP (m97/m114 regime). Single-buffered 24KB LDS.
// XOR chunk-swizzle: pre-swizzled global source -> linear global_load_lds dst ->
// XOR'd ds_read (verified conflict-free, round 3). 4 waves split along M (32 rows each).
// MFMA operands swapped (mfma(b,a) -> D^T): packed 8B epilogue stores.
template <bool ASYNC_A>
__global__ __launch_bounds__(256) void gemm1_kernel(
    const unsigned short* __restrict__ xb,    // bf16 [B][D] (ASYNC_A)
    const float* __restrict__ x,              // fp32 [B][D] (!ASYNC_A)
    const unsigned short* __restrict__ w1t,   // [E][H][D] bf16
    const float* __restrict__ b1,             // [E][H] fp32
    const int* __restrict__ cnt,
    const int* __restrict__ rowidx,
    unsigned short* __restrict__ hbuf,        // [32768][256] bf16 (packed by pos)
    int g0, int g1) {
  __shared__ unsigned short As[128 * 64];   // 16 KB
  __shared__ unsigned short Bs[64 * 64];    // 8 KB
  int t = blockIdx.x, g = -1, lt = 0;
#pragma unroll 1
  for (int gg = g0; gg < g1; gg++) {
    int nt = (cnt[gg] + 127) >> 7;
    if (t < nt) { g = gg; lt = t; break; }
    t -= nt;
  }
  if (g < 0) return;
  const int* offs = cnt + 32;
  int hb = offs[g0];
  int m0 = offs[g] + lt * 128;
  int mEnd = offs[g] + cnt[g];
  int e = g;
  int n0 = blockIdx.y * 64;
  const unsigned short* Bsrc = w1t + (size_t)e * HH * DD + (size_t)n0 * DD;
  int tid = threadIdx.x, lane = tid & 63, wv = tid >> 6;
  int wr = wv * 32;                      // wave's 32 output rows
  int lm = lane & 15, q = lane >> 4;
  int lm7 = lm & 7;
  floatx4 acc[2][4];
  floatx4 zero = {0.f, 0.f, 0.f, 0.f};
#pragma unroll
  for (int i = 0; i < 2; i++)
#pragma unroll
    for (int j = 0; j < 4; j++) acc[i][j] = zero;
  int srow = tid >> 3;                         // 0..31
  int ssrc = (((tid & 7) ^ (srow & 7))) * 8;   // swizzled source chunk (elems)
  int sdst = (tid & 7) * 8;                    // linear LDS slot (fp32 path)
  const unsigned short* gA[4];
  const float* gAf[4];
  const unsigned short* gBp[2];
#pragma unroll
  for (int i = 0; i < 4; i++) {
    int pos = m0 + i * 32 + srow;
    int grow = rowidx[pos < mEnd ? pos : m0];  // clamp: data discarded at epilogue
    if (ASYNC_A) gA[i] = xb + (size_t)grow * DD + ssrc;
    else         gAf[i] = x + (size_t)grow * DD + ssrc;
  }
#pragma unroll
  for (int i = 0; i < 2; i++)
    gBp[i] = Bsrc + (size_t)(i * 32 + srow) * DD + ssrc;
#pragma unroll 1
  for (int k0 = 0; k0 < DD; k0 += 64) {
    if (ASYNC_A) {
#pragma unroll
      for (int i = 0; i < 4; i++) async16(gA[i], &As[wv * 512 + i * 2048]);
#pragma unroll
      for (int i = 0; i < 4; i++) gA[i] += 64;
    } else {
#pragma unroll
      for (int i = 0; i < 4; i++) {
        float4 f0 = *(const float4*)gAf[i];
        float4 f1 = *(const float4*)(gAf[i] + 4);
        gAf[i] += 64;
        uint4 av;
        av.x = pack2(f0.x, f0.y); av.y = pack2(f0.z, f0.w);
        av.z = pack2(f1.x, f1.y); av.w = pack2(f1.z, f1.w);
        *(uint4*)&As[(i * 32 + srow) * 64 + sdst] = av;  // src swizzled, slot linear
      }
    }
#pragma unroll
    for (int i = 0; i < 2; i++) async16(gBp[i], &Bs[wv * 512 + i * 2048]);
#pragma unroll
    for (int i = 0; i < 2; i++) gBp[i] += 64;
    __syncthreads();
#pragma unroll
    for (int ks = 0; ks < 2; ks++) {
      short8 a[2], b[4];
#pragma unroll
      for (int i = 0; i < 2; i++)
        a[i] = *(const short8*)&As[(wr + i * 16 + lm) * 64 + ((ks * 4 + q) ^ lm7) * 8];
#pragma unroll
      for (int j = 0; j < 4; j++)
        b[j] = *(const short8*)&Bs[(j * 16 + lm) * 64 + ((ks * 4 + q) ^ lm7) * 8];
#pragma unroll
      for (int i = 0; i < 2; i++)
#pragma unroll
        for (int j = 0; j < 4; j++)
          acc[i][j] = __builtin_amdgcn_mfma_f32_16x16x32_bf16(b[j], a[i], acc[i][j], 0, 0, 0);
    }
    __syncthreads();
  }
  // D^T mapping: row m = wr+i*16+lm ; cols n = n0 + j*16 + q*4 + {0..3}
#pragma unroll
  for (int i = 0; i < 2; i++) {
    int pos = m0 + wr + i * 16 + lm;
    if (pos < mEnd) {
#pragma unroll
      for (int j = 0; j < 4; j++) {
        int col = n0 + j * 16 + q * 4;
        const float4 bb = *(const float4*)(b1 + e * HH + col);
        float v0 = acc[i][j][0] + bb.x;
        float v1 = acc[i][j][1] + bb.y;
        float v2 = acc[i][j][2] + bb.z;
        float v3 = acc[i][j][3] + bb.w;
        v0 = 0.5f * v0 * (1.f + erff(v0 * 0.70710678118654752f));  // exact GELU
        v1 = 0.5f * v1 * (1.f + erff(v1 * 0.70710678118654752f));
        v2 = 0.5f * v2 * (1.f + erff(v2 * 0.70710678118654752f));
        v3 = 0.5f * v3 * (1.f + erff(v3 * 0.70710678118654752f));
        uint2 st; st.x = pack2(v0, v1); st.y = pack2(v2, v3);
        *(uint2*)(hbuf + (size_t)(pos - hb) * HH + col) = st;
      }
    }
  }
}

// ---------------- grouped GEMM2: eo[pos] = bf16( w[pos] * (h @ w2[e] + b2[e]) ) ----------------
// Single-buffered (grid 2112 blocks -> TLP-rich; 64KB LDS would halve residency, m132).
// XOR chunk-swizzle on staging source + ds_read side.
// EO=true : packed bf16 rows to eo (no scatter, no RMW); combine_kernel finishes.
// EO=false: fallback, fp32 atomicAdd into zero-initialized out (2 commutative adds/elem).
template <bool EO>
__global__ __launch_bounds__(256) void gemm2_kernel(
    const unsigned short* __restrict__ hbuf,
    const unsigned short* __restrict__ w2t,   // [E][D][H] bf16
    const float* __restrict__ b2,             // [E][D] fp32
    const int* __restrict__ cnt,
    const int* __restrict__ rowidx,
    const float* __restrict__ wgt,
    unsigned short* __restrict__ eo,          // [32768][1024] bf16 (EO)
    float* out,                               // [B][D] fp32 (!EO)
    int g0, int g1) {
  __shared__ unsigned short As[128 * 64];
  __shared__ unsigned short Bs[128 * 64];
  int t = blockIdx.x, g = -1, lt = 0;
#pragma unroll 1
  for (int gg = g0; gg < g1; gg++) {
    int nt = (cnt[gg] + 127) >> 7;
    if (t < nt) { g = gg; lt = t; break; }
    t -= nt;
  }
  if (g < 0) return;
  const int* offs = cnt + 32;
  int hb = offs[g0];
  int m0 = offs[g] + lt * 128;
  int mEnd = offs[g] + cnt[g];
  int e = g;
  int n0 = blockIdx.y * 128;
  const unsigned short* Bsrc = w2t + (size_t)e * DD * HH + (size_t)n0 * HH;
  int tid = threadIdx.x, lane = tid & 63, wv = tid >> 6;
  int wr = (wv >> 1) * 64, wc = (wv & 1) * 64;
  int lm = lane & 15, q = lane >> 4;
  int lm7 = lm & 7;
  floatx4 acc[4][4];
  floatx4 zero = {0.f, 0.f, 0.f, 0.f};
#pragma unroll
  for (int i = 0; i < 4; i++)
#pragma unroll
    for (int j = 0; j < 4; j++) acc[i][j] = zero;
  int srow = tid >> 3;
  int ssrc = (((tid & 7) ^ (srow & 7))) * 8;   // swizzled source chunk
  const unsigned short* gA[4];
  const unsigned short* gBp[4];
#pragma unroll
  for (int i = 0; i < 4; i++) {
    int pos = m0 + i * 32 + srow;
    int posc = (pos < mEnd) ? pos : m0;       // clamp: discarded at epilogue
    gA[i] = hbuf + (size_t)(posc - hb) * HH + ssrc;
    gBp[i] = Bsrc + (size_t)(i * 32 + srow) * HH + ssrc;
  }
  unsigned short* AsW = As + wv * 512;
  unsigned short* BsW = Bs + wv * 512;
#pragma unroll 1
  for (int k0 = 0; k0 < HH; k0 += 64) {
#pragma unroll
    for (int i = 0; i < 4; i++) async16(gA[i], AsW + i * 2048);
#pragma unroll
    for (int i = 0; i < 4; i++) async16(gBp[i], BsW + i * 2048);
#pragma unroll
    for (int i = 0; i < 4; i++) { gA[i] += 64; gBp[i] += 64; }
    __syncthreads();
#pragma unroll
    for (int ks = 0; ks < 2; ks++) {
      short8 a[4], b[4];
#pragma unroll
      for (int i = 0; i < 4; i++)
        a[i] = *(const short8*)&As[(wr + i * 16 + lm) * 64 + ((ks * 4 + q) ^ lm7) * 8];
#pragma unroll
      for (int j = 0; j < 4; j++)
        b[j] = *(const short8*)&Bs[(wc + j * 16 + lm) * 64 + ((ks * 4 + q) ^ lm7) * 8];
#pragma unroll
      for (int i = 0; i < 4; i++)
#pragma unroll
        for (int j = 0; j < 4; j++)
          acc[i][j] = __builtin_amdgcn_mfma_f32_16x16x32_bf16(b[j], a[i], acc[i][j], 0, 0, 0);
    }
    __syncthreads();
  }
  // D^T mapping: row m = wr+i*16+lm ; cols n = wc + j*16 + q*4 + {0..3}
#pragma unroll
  for (int i = 0; i < 4; i++) {
    int pos = m0 + wr + i * 16 + lm;
    if (pos < mEnd) {
      float wrow = wgt[pos];
      if (EO) {
#pragma unroll
        for (int j = 0; j < 4; j++) {
          int col = n0 + wc + j * 16 + q * 4;
          const float4 bb = *(const float4*)(b2 + e * DD + col);
          uint2 st;
          st.x = pack2((acc[i][j][0] + bb.x) * wrow, (acc[i][j][1] + bb.y) * wrow);
          st.y = pack2((acc[i][j][2] + bb.z) * wrow, (acc[i][j][3] + bb.w) * wrow);
          *(uint2*)(eo + (size_t)pos * DD + col) = st;
        }
      } else {
        int grow = rowidx[pos];
#pragma unroll
        for (int j = 0; j < 4; j++) {
          int col = n0 + wc + j * 16 + q * 4;
          const float4 bb = *(const float4*)(b2 + e * DD + col);
          float* op = out + (size_t)grow * DD + col;
          atomicAdd(op + 0, (acc[i][j][0] + bb.x) * wrow);
          atomicAdd(op + 1, (acc[i][j][1] + bb.y) * wrow);
          atomicAdd(op + 2, (acc[i][j][2] + bb.z) * wrow);
          atomicAdd(op + 3, (acc[i][j][3] + bb.w) * wrow);
        }
      }
    }
  }
}

// ---------------- combine: out[row] = eo[p0] + eo[p1] (weights pre-applied) ----------------
__global__ __launch_bounds__(256) void combine_kernel(
    const unsigned short* __restrict__ eo, const int* __restrict__ posmap,
    float* __restrict__ out) {
  int row = blockIdx.x * 2 + (threadIdx.x >> 7);
  int t = threadIdx.x & 127;
  int p0 = posmap[row * 2 + 0];
  int p1 = posmap[row * 2 + 1];
  uint4 av = *((const uint4*)(eo + (size_t)p0 * DD) + t);
  uint4 bv = *((const uint4*)(eo + (size_t)p1 * DD) + t);
  unsigned int ua[4] = {av.x, av.y, av.z, av.w};
  unsigned int ub[4] = {bv.x, bv.y, bv.z, bv.w};
  float o[8];
#pragma unroll
  for (int k = 0; k < 4; k++) {
    o[2 * k]     = bf2f(ua[k] & 0xffffu) + bf2f(ub[k] & 0xffffu);
    o[2 * k + 1] = bf2f(ua[k] >> 16)     + bf2f(ub[k] >> 16);
  }
  float* op = out + (size_t)row * DD + t * 8;
  *(float4*)(op)     = make_float4(o[0], o[1], o[2], o[3]);
  *(float4*)(op + 4) = make_float4(o[4], o[5], o[6], o[7]);
}

extern "C" void kernel_launch(void* const* d_in, const int* in_sizes, int n_in,
                              void* d_out, int out_size, void* d_ws, size_t ws_size,
                              hipStream_t stream) {
  (void)in_sizes; (void)n_in; (void)out_size;
  const float* x      = (const float*)d_in[0];
  const float* gate_w = (const float*)d_in[1];
  const float* gate_b = (const float*)d_in[2];
  const float* w1     = (const float*)d_in[3];
  const float* b1     = (const float*)d_in[4];
  const float* w2     = (const float*)d_in[5];
  const float* b2     = (const float*)d_in[6];
  float* out = (float*)d_out;

  char* w = (char*)d_ws;
  int* cnt            = (int*)(w);                 // 48 ints (cnt[0..7], offs at +32)
  int* rinfo_e        = (int*)(w + 256);           // [16384]
  float* rinfo_w      = (float*)(w + 65792);       // [32768]
  int* posmap         = (int*)(w + 65792);         // aliases rinfo_w (safe: in-thread RAW order)
  int* bhist          = (int*)(w + 196864);        // [1024][8]
  int* bbase          = (int*)(w + 229632);        // [1024][8]
  int* rowidx         = (int*)(w + 262400);        // [32768]
  float* wgt          = (float*)(w + 393472);      // [32768]
  unsigned short* w1t = (unsigned short*)(w + 524544);   // 4 MB bf16
  unsigned short* w2t = (unsigned short*)(w + 4718848);  // 4 MB bf16
  unsigned short* hbuf= (unsigned short*)(w + 8913152);  // 16 MB bf16 [32768][256]
  unsigned short* xb  = (unsigned short*)(w + 25690368); // 32 MB bf16
  unsigned short* eo  = (unsigned short*)(w + 59244800); // 64 MB bf16 [32768][1024]
  bool use_xb = ws_size >= (size_t)59244800;
  bool use_eo = ws_size >= (size_t)126353664;

  transpose_kernel<<<dim3(HH / 32, DD / 32, EE), dim3(32, 8), 0, stream>>>(w1, w1t, DD, HH);
  transpose_kernel<<<dim3(DD / 32, HH / 32, EE), dim3(32, 8), 0, stream>>>(w2, w2t, HH, DD);
  gating_kernel<<<GB, 256, 0, stream>>>(x, gate_w, gate_b, rinfo_e, rinfo_w, bhist,
                                        use_xb ? xb : (unsigned short*)nullptr);
  scan_kernel<<<1, 256, 0, stream>>>(bhist, cnt, bbase);
  scatter_kernel<<<GB, 64, 0, stream>>>(rinfo_e, rinfo_w, bbase, rowidx, wgt, posmap);
  // m-tiles over 8 merged groups: sum(ceil(cnt_e/128)) <= 256+7 = 263 -> grid.x = 264
  if (use_eo) {
    gemm1_kernel<true><<<dim3(264, 4), 256, 0, stream>>>(xb, x, w1t, b1, cnt, rowidx, hbuf, 0, 8);
    gemm2_kernel<true><<<dim3(264, 8), 256, 0, stream>>>(hbuf, w2t, b2, cnt, rowidx, wgt, eo, nullptr, 0, 8);
    combine_kernel<<<BN / 2, 256, 0, stream>>>(eo, posmap, out);
  } else if (use_xb) {
    hipMemsetAsync(out, 0, (size_t)BN * DD * 4, stream);
    gemm1_kernel<true><<<dim3(264, 4), 256, 0, stream>>>(xb, x, w1t, b1, cnt, rowidx, hbuf, 0, 8);
    gemm2_kernel<false><<<dim3(264, 8), 256, 0, stream>>>(hbuf, w2t, b2, cnt, rowidx, wgt, nullptr, out, 0, 8);
  } else {
    hipMemsetAsync(out, 0, (size_t)BN * DD * 4, stream);
    gemm1_kernel<false><<<dim3(264, 4), 256, 0, stream>>>(nullptr, x, w1t, b1, cnt, rowidx, hbuf, 0, 8);
    gemm2_kernel<false><<<dim3(264, 8), 256, 0, stream>>>(hbuf, w2t, b2, cnt, rowidx, wgt, nullptr, out, 0, 8);
  }
}

// Round 6
// 282.806 us; speedup vs baseline: 1.0145x; 1.0145x over previous
//
#include <hip/hip_runtime.h>
#include <stdint.h>

#define BN 16384
#define DD 1024
#define HH 256
#define EE 8
#define GB 1024  // gating blocks
#define GR 16    // rows per gating block

typedef __attribute__((ext_vector_type(8))) short short8;
typedef __attribute__((ext_vector_type(4))) float floatx4;

__device__ __forceinline__ unsigned short f2bf(float f) {
  union { float f; unsigned int i; } v; v.f = f;
  unsigned int x = v.i;
  x += 0x7fffu + ((x >> 16) & 1u);  // RTNE
  return (unsigned short)(x >> 16);
}
__device__ __forceinline__ unsigned int pack2(float a, float b) {
  return (unsigned int)f2bf(a) | ((unsigned int)f2bf(b) << 16);
}
__device__ __forceinline__ float bf2f(unsigned int u16) {
  union { unsigned int i; float f; } v; v.i = u16 << 16; return v.f;
}
// async 16B/lane global->LDS DMA; lds dst must be wave-uniform base (+lane*16 by HW)
__device__ __forceinline__ void async16(const unsigned short* g, unsigned short* l) {
  __builtin_amdgcn_global_load_lds(
      (const __attribute__((address_space(1))) void*)g,
      (__attribute__((address_space(3))) void*)l, 16, 0, 0);
}

// ---------------- gate_w [1024][8] -> gwt [8][1024] (fp32, 32 KB) ----------------
// gwt lives in the first 32KB of hbuf: gating reads it; gemm1 overwrites hbuf later
// (same stream => ordered). Kills the 128B-stride segmented loads in gating.
__global__ __launch_bounds__(256) void transpose_gw_kernel(
    const float* __restrict__ gate_w, float* __restrict__ gwt) {
  int idx = blockIdx.x * 256 + threadIdx.x;   // 8192 elements
  int d = idx >> 3, e = idx & 7;
  gwt[e * DD + d] = gate_w[idx];
}

// ---------------- gating: fp32 logits -> top2 -> rinfo + per-block histogram ----------------
// merged grouping: one list per expert (8 groups); a row contributes to both its experts' bins
// Also converts x -> bf16 xb on the fly. Gate matrix read via gwt[8][1024]:
// for fixed e the 64 lanes load CONTIGUOUS float4s (8 L1 lines/instr vs 64 segmented).
__global__ __launch_bounds__(256) void gating_kernel(
    const float* __restrict__ x,
    const float* __restrict__ gwt,       // [8][1024] fp32
    const float* __restrict__ gate_b,
    int* __restrict__ rinfo_e, float* __restrict__ rinfo_w,
    int* __restrict__ bhist,
    unsigned short* __restrict__ xb) {   // nullable
  __shared__ int hist[EE];
  int tid = threadIdx.x;
  if (tid < EE) hist[tid] = 0;
  __syncthreads();
  int lane = tid & 63, wv = tid >> 6;
  int p0 = lane & 1, p1 = (lane >> 1) & 1, p2 = (lane >> 2) & 1;
  float gb[EE];
#pragma unroll
  for (int e = 0; e < EE; e++) gb[e] = gate_b[e];
#pragma unroll 1
  for (int it = 0; it < GR / 4; it++) {
    int row = blockIdx.x * GR + it * 4 + wv;
    const float4* xr4 = (const float4*)(x + (size_t)row * DD);
    float acc[EE];
#pragma unroll
    for (int e = 0; e < EE; e++) acc[e] = 0.f;
#pragma unroll
    for (int i = 0; i < 4; i++) {
      int d4 = lane + i * 64;  // float4 index
      float4 xv = xr4[d4];
      if (xb) {
        uint2 st; st.x = pack2(xv.x, xv.y); st.y = pack2(xv.z, xv.w);
        *(uint2*)(xb + (size_t)row * DD + (size_t)d4 * 4) = st;
      }
      const float4* gT = (const float4*)gwt + d4;  // + e*256 per expert row
#pragma unroll
      for (int e = 0; e < EE; e++) {
        float4 ge = gT[e * (DD / 4)];
        acc[e] += xv.x * ge.x + xv.y * ge.y + xv.z * ge.z + xv.w * ge.w;
      }
    }
    // reduce-scatter: halve live values 8->4->2->1 (4+2+1 shuffles),
    // then 3-stage butterfly across 8-lane groups. Lane ends holding the
    // full sum for expert e(lane) = ((lane&1)<<2) | (lane&2) | ((lane>>2)&1).
    float v4[4];
#pragma unroll
    for (int k = 0; k < 4; k++) {
      float send = p0 ? acc[k] : acc[k + 4];        // value the partner keeps
      float recv = __shfl_xor(send, 1, 64);
      v4[k] = (p0 ? acc[k + 4] : acc[k]) + recv;
    }
    float v2[2];
#pragma unroll
    for (int k = 0; k < 2; k++) {
      float send = p1 ? v4[k] : v4[k + 2];
      float recv = __shfl_xor(send, 2, 64);
      v2[k] = (p1 ? v4[k + 2] : v4[k]) + recv;
    }
    float v1;
    {
      float send = p2 ? v2[0] : v2[1];
      float recv = __shfl_xor(send, 4, 64);
      v1 = (p2 ? v2[1] : v2[0]) + recv;
    }
    v1 += __shfl_xor(v1, 8, 64);
    v1 += __shfl_xor(v1, 16, 64);
    v1 += __shfl_xor(v1, 32, 64);
    // gather logits (mapping is an involution: laneFor(e) uses same formula)
    float lg[EE];
#pragma unroll
    for (int e = 0; e < EE; e++) {
      int src = ((e & 1) << 2) | (e & 2) | ((e >> 2) & 1);
      lg[e] = __shfl(v1, src, 64) + gb[e];
    }
    if (lane == 0) {
      int i1 = 0;
      for (int e = 1; e < EE; e++) if (lg[e] > lg[i1]) i1 = e;
      int i2 = (i1 == 0) ? 1 : 0;
      for (int e = 0; e < EE; e++) if (e != i1 && lg[e] > lg[i2]) i2 = e;
      float wA = 1.f / (1.f + __expf(lg[i2] - lg[i1]));  // p1/(p1+p2), arg <= 0
      float wB = 1.f - wA;
      rinfo_e[row] = i1 | (i2 << 8);
      rinfo_w[row * 2 + 0] = wA;
      rinfo_w[row * 2 + 1] = wB;
      atomicAdd(&hist[i1], 1);      // LDS atomics only
      atomicAdd(&hist[i2], 1);
    }
  }
  __syncthreads();
  if (tid < EE) bhist[blockIdx.x * EE + tid] = hist[tid];
}

// ---------------- scan: totals, group offsets, per-block bases (deterministic) ----------------
__global__ __launch_bounds__(256) void scan_kernel(
    const int* __restrict__ bhist, int* __restrict__ cnt, int* __restrict__ bbase) {
  __shared__ int cs[32][EE];
  __shared__ int ofs[EE];
  int tid = threadIdx.x;
  int g = tid & 7, c = tid >> 3;   // 32 chunks of 32 blocks (GB=1024)
  int s = 0;
#pragma unroll 1
  for (int b = c * 32; b < c * 32 + 32; b++) s += bhist[b * EE + g];
  cs[c][g] = s;
  __syncthreads();
  if (tid == 0) {
    int run = 0;
    for (int gg = 0; gg < EE; gg++) {
      int tot = 0;
      for (int cc = 0; cc < 32; cc++) tot += cs[cc][gg];
      cnt[gg] = tot;
      cnt[32 + gg] = run;
      ofs[gg] = run;
      run += tot;
    }
  }
  __syncthreads();
  if (tid < EE) {
    int run = ofs[tid];
#pragma unroll 1
    for (int cc = 0; cc < 32; cc++) { int t = cs[cc][tid]; cs[cc][tid] = run; run += t; }
  }
  __syncthreads();
  int run = cs[c][g];
#pragma unroll 1
  for (int b = c * 32; b < c * 32 + 32; b++) {
    bbase[b * EE + g] = run;
    run += bhist[b * EE + g];
  }
}

// ---------------- scatter (also writes inverse map row -> (p0,p1)) ----------------
// NOTE: posmap may alias rinfo_w; reads of rinfo_w happen before posmap writes in-thread.
__global__ __launch_bounds__(64) void scatter_kernel(
    const int* __restrict__ rinfo_e, const float* rinfo_w,
    const int* __restrict__ bbase,
    int* __restrict__ rowidx, float* __restrict__ wgt, int* posmap) {
  __shared__ int curs[EE];
  int tid = threadIdx.x;
  if (tid < EE) curs[tid] = bbase[blockIdx.x * EE + tid];
  __syncthreads();
  if (tid < GR) {
    int row = blockIdx.x * GR + tid;
    int ee = rinfo_e[row];
    int e0 = ee & 255, e1 = (ee >> 8) & 255;
    float w0 = rinfo_w[row * 2 + 0];
    float w1 = rinfo_w[row * 2 + 1];
    int p0 = atomicAdd(&curs[e0], 1);
    rowidx[p0] = row; wgt[p0] = w0;
    int p1 = atomicAdd(&curs[e1], 1);
    rowidx[p1] = row; wgt[p1] = w1;
    posmap[row * 2 + 0] = p0;
    posmap[row * 2 + 1] = p1;
  }
}

// src fp32 [E][R][C] -> dst bf16 [E][C][R]
__global__ void transpose_kernel(const float* __restrict__ src,
                                 unsigned short* __restrict__ dst, int R, int C) {
  __shared__ float tbuf[32][33];
  int e = blockIdx.z;
  int c0 = blockIdx.x * 32, r0 = blockIdx.y * 32;
  int tx = threadIdx.x, ty = threadIdx.y;
  const float* s = src + (size_t)e * R * C;
  unsigned short* d = dst + (size_t)e * R * C;
  for (int yy = ty; yy < 32; yy += 8)
    tbuf[yy][tx] = s[(size_t)(r0 + yy) * C + c0 + tx];
  __syncthreads();
  for (int yy = ty; yy < 32; yy += 8)
    d[(size_t)(c0 + yy) * R + r0 + tx] = f2bf(tbuf[tx][yy]);
}

// ---------------- grouped GEMM1: h = gelu(Xg @ w1[e] + b1[e]) ----------------
// 128(M)x64(N) tile, grid (264,4) = 1056 blocks -> ~4 blocks/CU (16 waves/CU):
// latency hidden by cross-block TLP (m97/m114 regime). Single-buffered 24KB LDS.
// XOR chunk-swizzle: pre-swizzled global source -> linear global_load_lds dst ->
// XOR'd ds_read (verified conflict-free, round 3). 4 waves split along M (32 rows each).
// MFMA operands swapped (mfma(b,a) -> D^T): packed 8B epilogue stores.
template <bool ASYNC_A>
__global__ __launch_bounds__(256) void gemm1_kernel(
    const unsigned short* __restrict__ xb,    // bf16 [B][D] (ASYNC_A)
    const float* __restrict__ x,              // fp32 [B][D] (!ASYNC_A)
    const unsigned short* __restrict__ w1t,   // [E][H][D] bf16
    const float* __restrict__ b1,             // [E][H] fp32
    const int* __restrict__ cnt,
    const int* __restrict__ rowidx,
    unsigned short* __restrict__ hbuf,        // [32768][256] bf16 (packed by pos)
    int g0, int g1) {
  __shared__ unsigned short As[128 * 64];   // 16 KB
  __shared__ unsigned short Bs[64 * 64];    // 8 KB
  int t = blockIdx.x, g = -1, lt = 0;
#pragma unroll 1
  for (int gg = g0; gg < g1; gg++) {
    int nt = (cnt[gg] + 127) >> 7;
    if (t < nt) { g = gg; lt = t; break; }
    t -= nt;
  }
  if (g < 0) return;
  const int* offs = cnt + 32;
  int hb = offs[g0];
  int m0 = offs[g] + lt * 128;
  int mEnd = offs[g] + cnt[g];
  int e = g;
  int n0 = blockIdx.y * 64;
  const unsigned short* Bsrc = w1t + (size_t)e * HH * DD + (size_t)n0 * DD;
  int tid = threadIdx.x, lane = tid & 63, wv = tid >> 6;
  int wr = wv * 32;                      // wave's 32 output rows
  int lm = lane & 15, q = lane >> 4;
  int lm7 = lm & 7;
  floatx4 acc[2][4];
  floatx4 zero = {0.f, 0.f, 0.f, 0.f};
#pragma unroll
  for (int i = 0; i < 2; i++)
#pragma unroll
    for (int j = 0; j < 4; j++) acc[i][j] = zero;
  int srow = tid >> 3;                         // 0..31
  int ssrc = (((tid & 7) ^ (srow & 7))) * 8;   // swizzled source chunk (elems)
  int sdst = (tid & 7) * 8;                    // linear LDS slot (fp32 path)
  const unsigned short* gA[4];
  const float* gAf[4];
  const unsigned short* gBp[2];
#pragma unroll
  for (int i = 0; i < 4; i++) {
    int pos = m0 + i * 32 + srow;
    int grow = rowidx[pos < mEnd ? pos : m0];  // clamp: data discarded at epilogue
    if (ASYNC_A) gA[i] = xb + (size_t)grow * DD + ssrc;
    else         gAf[i] = x + (size_t)grow * DD + ssrc;
  }
#pragma unroll
  for (int i = 0; i < 2; i++)
    gBp[i] = Bsrc + (size_t)(i * 32 + srow) * DD + ssrc;
#pragma unroll 1
  for (int k0 = 0; k0 < DD; k0 += 64) {
    if (ASYNC_A) {
#pragma unroll
      for (int i = 0; i < 4; i++) async16(gA[i], &As[wv * 512 + i * 2048]);
#pragma unroll
      for (int i = 0; i < 4; i++) gA[i] += 64;
    } else {
#pragma unroll
      for (int i = 0; i < 4; i++) {
        float4 f0 = *(const float4*)gAf[i];
        float4 f1 = *(const float4*)(gAf[i] + 4);
        gAf[i] += 64;
        uint4 av;
        av.x = pack2(f0.x, f0.y); av.y = pack2(f0.z, f0.w);
        av.z = pack2(f1.x, f1.y); av.w = pack2(f1.z, f1.w);
        *(uint4*)&As[(i * 32 + srow) * 64 + sdst] = av;  // src swizzled, slot linear
      }
    }
#pragma unroll
    for (int i = 0; i < 2; i++) async16(gBp[i], &Bs[wv * 512 + i * 2048]);
#pragma unroll
    for (int i = 0; i < 2; i++) gBp[i] += 64;
    __syncthreads();
#pragma unroll
    for (int ks = 0; ks < 2; ks++) {
      short8 a[2], b[4];
#pragma unroll
      for (int i = 0; i < 2; i++)
        a[i] = *(const short8*)&As[(wr + i * 16 + lm) * 64 + ((ks * 4 + q) ^ lm7) * 8];
#pragma unroll
      for (int j = 0; j < 4; j++)
        b[j] = *(const short8*)&Bs[(j * 16 + lm) * 64 + ((ks * 4 + q) ^ lm7) * 8];
#pragma unroll
      for (int i = 0; i < 2; i++)
#pragma unroll
        for (int j = 0; j < 4; j++)
          acc[i][j] = __builtin_amdgcn_mfma_f32_16x16x32_bf16(b[j], a[i], acc[i][j], 0, 0, 0);
    }
    __syncthreads();
  }
  // D^T mapping: row m = wr+i*16+lm ; cols n = n0 + j*16 + q*4 + {0..3}
#pragma unroll
  for (int i = 0; i < 2; i++) {
    int pos = m0 + wr + i * 16 + lm;
    if (pos < mEnd) {
#pragma unroll
      for (int j = 0; j < 4; j++) {
        int col = n0 + j * 16 + q * 4;
        const float4 bb = *(const float4*)(b1 + e * HH + col);
        float v0 = acc[i][j][0] + bb.x;
        float v1 = acc[i][j][1] + bb.y;
        float v2 = acc[i][j][2] + bb.z;
        float v3 = acc[i][j][3] + bb.w;
        v0 = 0.5f * v0 * (1.f + erff(v0 * 0.70710678118654752f));  // exact GELU
        v1 = 0.5f * v1 * (1.f + erff(v1 * 0.70710678118654752f));
        v2 = 0.5f * v2 * (1.f + erff(v2 * 0.70710678118654752f));
        v3 = 0.5f * v3 * (1.f + erff(v3 * 0.70710678118654752f));
        uint2 st; st.x = pack2(v0, v1); st.y = pack2(v2, v3);
        *(uint2*)(hbuf + (size_t)(pos - hb) * HH + col) = st;
      }
    }
  }
}

// ---------------- grouped GEMM2: eo[pos] = bf16( w[pos] * (h @ w2[e] + b2[e]) ) ----------------
// Single-buffered (grid 2112 blocks -> TLP-rich; 64KB LDS would halve residency, m132).
// XOR chunk-swizzle on staging source + ds_read side.
// EO=true : packed bf16 rows to eo (no scatter, no RMW); combine_kernel finishes.
// EO=false: fallback, fp32 atomicAdd into zero-initialized out (2 commutative adds/elem).
template <bool EO>
__global__ __launch_bounds__(256) void gemm2_kernel(
    const unsigned short* __restrict__ hbuf,
    const unsigned short* __restrict__ w2t,   // [E][D][H] bf16
    const float* __restrict__ b2,             // [E][D] fp32
    const int* __restrict__ cnt,
    const int* __restrict__ rowidx,
    const float* __restrict__ wgt,
    unsigned short* __restrict__ eo,          // [32768][1024] bf16 (EO)
    float* out,                               // [B][D] fp32 (!EO)
    int g0, int g1) {
  __shared__ unsigned short As[128 * 64];
  __shared__ unsigned short Bs[128 * 64];
  int t = blockIdx.x, g = -1, lt = 0;
#pragma unroll 1
  for (int gg = g0; gg < g1; gg++) {
    int nt = (cnt[gg] + 127) >> 7;
    if (t < nt) { g = gg; lt = t; break; }
    t -= nt;
  }
  if (g < 0) return;
  const int* offs = cnt + 32;
  int hb = offs[g0];
  int m0 = offs[g] + lt * 128;
  int mEnd = offs[g] + cnt[g];
  int e = g;
  int n0 = blockIdx.y * 128;
  const unsigned short* Bsrc = w2t + (size_t)e * DD * HH + (size_t)n0 * HH;
  int tid = threadIdx.x, lane = tid & 63, wv = tid >> 6;
  int wr = (wv >> 1) * 64, wc = (wv & 1) * 64;
  int lm = lane & 15, q = lane >> 4;
  int lm7 = lm & 7;
  floatx4 acc[4][4];
  floatx4 zero = {0.f, 0.f, 0.f, 0.f};
#pragma unroll
  for (int i = 0; i < 4; i++)
#pragma unroll
    for (int j = 0; j < 4; j++) acc[i][j] = zero;
  int srow = tid >> 3;
  int ssrc = (((tid & 7) ^ (srow & 7))) * 8;   // swizzled source chunk
  const unsigned short* gA[4];
  const unsigned short* gBp[4];
#pragma unroll
  for (int i = 0; i < 4; i++) {
    int pos = m0 + i * 32 + srow;
    int posc = (pos < mEnd) ? pos : m0;       // clamp: discarded at epilogue
    gA[i] = hbuf + (size_t)(posc - hb) * HH + ssrc;
    gBp[i] = Bsrc + (size_t)(i * 32 + srow) * HH + ssrc;
  }
  unsigned short* AsW = As + wv * 512;
  unsigned short* BsW = Bs + wv * 512;
#pragma unroll 1
  for (int k0 = 0; k0 < HH; k0 += 64) {
#pragma unroll
    for (int i = 0; i < 4; i++) async16(gA[i], AsW + i * 2048);
#pragma unroll
    for (int i = 0; i < 4; i++) async16(gBp[i], BsW + i * 2048);
#pragma unroll
    for (int i = 0; i < 4; i++) { gA[i] += 64; gBp[i] += 64; }
    __syncthreads();
#pragma unroll
    for (int ks = 0; ks < 2; ks++) {
      short8 a[4], b[4];
#pragma unroll
      for (int i = 0; i < 4; i++)
        a[i] = *(const short8*)&As[(wr + i * 16 + lm) * 64 + ((ks * 4 + q) ^ lm7) * 8];
#pragma unroll
      for (int j = 0; j < 4; j++)
        b[j] = *(const short8*)&Bs[(wc + j * 16 + lm) * 64 + ((ks * 4 + q) ^ lm7) * 8];
#pragma unroll
      for (int i = 0; i < 4; i++)
#pragma unroll
        for (int j = 0; j < 4; j++)
          acc[i][j] = __builtin_amdgcn_mfma_f32_16x16x32_bf16(b[j], a[i], acc[i][j], 0, 0, 0);
    }
    __syncthreads();
  }
  // D^T mapping: row m = wr+i*16+lm ; cols n = wc + j*16 + q*4 + {0..3}
#pragma unroll
  for (int i = 0; i < 4; i++) {
    int pos = m0 + wr + i * 16 + lm;
    if (pos < mEnd) {
      float wrow = wgt[pos];
      if (EO) {
#pragma unroll
        for (int j = 0; j < 4; j++) {
          int col = n0 + wc + j * 16 + q * 4;
          const float4 bb = *(const float4*)(b2 + e * DD + col);
          uint2 st;
          st.x = pack2((acc[i][j][0] + bb.x) * wrow, (acc[i][j][1] + bb.y) * wrow);
          st.y = pack2((acc[i][j][2] + bb.z) * wrow, (acc[i][j][3] + bb.w) * wrow);
          *(uint2*)(eo + (size_t)pos * DD + col) = st;
        }
      } else {
        int grow = rowidx[pos];
#pragma unroll
        for (int j = 0; j < 4; j++) {
          int col = n0 + wc + j * 16 + q * 4;
          const float4 bb = *(const float4*)(b2 + e * DD + col);
          float* op = out + (size_t)grow * DD + col;
          atomicAdd(op + 0, (acc[i][j][0] + bb.x) * wrow);
          atomicAdd(op + 1, (acc[i][j][1] + bb.y) * wrow);
          atomicAdd(op + 2, (acc[i][j][2] + bb.z) * wrow);
          atomicAdd(op + 3, (acc[i][j][3] + bb.w) * wrow);
        }
      }
    }
  }
}

// ---------------- combine: out[row] = eo[p0] + eo[p1] (weights pre-applied) ----------------
__global__ __launch_bounds__(256) void combine_kernel(
    const unsigned short* __restrict__ eo, const int* __restrict__ posmap,
    float* __restrict__ out) {
  int row = blockIdx.x * 2 + (threadIdx.x >> 7);
  int t = threadIdx.x & 127;
  int p0 = posmap[row * 2 + 0];
  int p1 = posmap[row * 2 + 1];
  uint4 av = *((const uint4*)(eo + (size_t)p0 * DD) + t);
  uint4 bv = *((const uint4*)(eo + (size_t)p1 * DD) + t);
  unsigned int ua[4] = {av.x, av.y, av.z, av.w};
  unsigned int ub[4] = {bv.x, bv.y, bv.z, bv.w};
  float o[8];
#pragma unroll
  for (int k = 0; k < 4; k++) {
    o[2 * k]     = bf2f(ua[k] & 0xffffu) + bf2f(ub[k] & 0xffffu);
    o[2 * k + 1] = bf2f(ua[k] >> 16)     + bf2f(ub[k] >> 16);
  }
  float* op = out + (size_t)row * DD + t * 8;
  *(float4*)(op)     = make_float4(o[0], o[1], o[2], o[3]);
  *(float4*)(op + 4) = make_float4(o[4], o[5], o[6], o[7]);
}

extern "C" void kernel_launch(void* const* d_in, const int* in_sizes, int n_in,
                              void* d_out, int out_size, void* d_ws, size_t ws_size,
                              hipStream_t stream) {
  (void)in_sizes; (void)n_in; (void)out_size;
  const float* x      = (const float*)d_in[0];
  const float* gate_w = (const float*)d_in[1];
  const float* gate_b = (const float*)d_in[2];
  const float* w1     = (const float*)d_in[3];
  const float* b1     = (const float*)d_in[4];
  const float* w2     = (const float*)d_in[5];
  const float* b2     = (const float*)d_in[6];
  float* out = (float*)d_out;

  char* w = (char*)d_ws;
  int* cnt            = (int*)(w);                 // 48 ints (cnt[0..7], offs at +32)
  int* rinfo_e        = (int*)(w + 256);           // [16384]
  float* rinfo_w      = (float*)(w + 65792);       // [32768]
  int* posmap         = (int*)(w + 65792);         // aliases rinfo_w (safe: in-thread RAW order)
  int* bhist          = (int*)(w + 196864);        // [1024][8]
  int* bbase          = (int*)(w + 229632);        // [1024][8]
  int* rowidx         = (int*)(w + 262400);        // [32768]
  float* wgt          = (float*)(w + 393472);      // [32768]
  unsigned short* w1t = (unsigned short*)(w + 524544);   // 4 MB bf16
  unsigned short* w2t = (unsigned short*)(w + 4718848);  // 4 MB bf16
  unsigned short* hbuf= (unsigned short*)(w + 8913152);  // 16 MB bf16 [32768][256]
  unsigned short* xb  = (unsigned short*)(w + 25690368); // 32 MB bf16
  unsigned short* eo  = (unsigned short*)(w + 59244800); // 64 MB bf16 [32768][1024]
  float* gwt          = (float*)hbuf;   // 32 KB, consumed by gating BEFORE gemm1 writes hbuf
  bool use_xb = ws_size >= (size_t)59244800;
  bool use_eo = ws_size >= (size_t)126353664;

  transpose_kernel<<<dim3(HH / 32, DD / 32, EE), dim3(32, 8), 0, stream>>>(w1, w1t, DD, HH);
  transpose_kernel<<<dim3(DD / 32, HH / 32, EE), dim3(32, 8), 0, stream>>>(w2, w2t, HH, DD);
  transpose_gw_kernel<<<32, 256, 0, stream>>>(gate_w, gwt);
  gating_kernel<<<GB, 256, 0, stream>>>(x, gwt, gate_b, rinfo_e, rinfo_w, bhist,
                                        use_xb ? xb : (unsigned short*)nullptr);
  scan_kernel<<<1, 256, 0, stream>>>(bhist, cnt, bbase);
  scatter_kernel<<<GB, 64, 0, stream>>>(rinfo_e, rinfo_w, bbase, rowidx, wgt, posmap);
  // m-tiles over 8 merged groups: sum(ceil(cnt_e/128)) <= 256+7 = 263 -> grid.x = 264
  if (use_eo) {
    gemm1_kernel<true><<<dim3(264, 4), 256, 0, stream>>>(xb, x, w1t, b1, cnt, rowidx, hbuf, 0, 8);
    gemm2_kernel<true><<<dim3(264, 8), 256, 0, stream>>>(hbuf, w2t, b2, cnt, rowidx, wgt, eo, nullptr, 0, 8);
    combine_kernel<<<BN / 2, 256, 0, stream>>>(eo, posmap, out);
  } else if (use_xb) {
    hipMemsetAsync(out, 0, (size_t)BN * DD * 4, stream);
    gemm1_kernel<true><<<dim3(264, 4), 256, 0, stream>>>(xb, x, w1t, b1, cnt, rowidx, hbuf, 0, 8);
    gemm2_kernel<false><<<dim3(264, 8), 256, 0, stream>>>(hbuf, w2t, b2, cnt, rowidx, wgt, nullptr, out, 0, 8);
  } else {
    hipMemsetAsync(out, 0, (size_t)BN * DD * 4, stream);
    gemm1_kernel<false><<<dim3(264, 4), 256, 0, stream>>>(nullptr, x, w1t, b1, cnt, rowidx, hbuf, 0, 8);
    gemm2_kernel<false><<<dim3(264, 8), 256, 0, stream>>>(hbuf, w2t, b2, cnt, rowidx, wgt, nullptr, out, 0, 8);
  }
}

// Round 7
// 275.920 us; speedup vs baseline: 1.0398x; 1.0250x over previous
//
#include <hip/hip_runtime.h>
#include <stdint.h>

#define BN 16384
#define DD 1024
#define HH 256
#define EE 8
#define GB 1024  // gating blocks
#define GR 16    // rows per gating block

typedef __attribute__((ext_vector_type(8))) short short8;
typedef __attribute__((ext_vector_type(4))) float floatx4;

__device__ __forceinline__ unsigned short f2bf(float f) {
  union { float f; unsigned int i; } v; v.f = f;
  unsigned int x = v.i;
  x += 0x7fffu + ((x >> 16) & 1u);  // RTNE
  return (unsigned short)(x >> 16);
}
__device__ __forceinline__ unsigned int pack2(float a, float b) {
  return (unsigned int)f2bf(a) | ((unsigned int)f2bf(b) << 16);
}
__device__ __forceinline__ float bf2f(unsigned int u16) {
  union { unsigned int i; float f; } v; v.i = u16 << 16; return v.f;
}
// async 16B/lane global->LDS DMA; lds dst must be wave-uniform base (+lane*16 by HW)
__device__ __forceinline__ void async16(const unsigned short* g, unsigned short* l) {
  __builtin_amdgcn_global_load_lds(
      (const __attribute__((address_space(1))) void*)g,
      (__attribute__((address_space(3))) void*)l, 16, 0, 0);
}

// ---------------- gating: fp32 logits -> top2 -> rinfo + per-block histogram ----------------
// Restructured (r7): gate_w staged to LDS (transposed, padded stride) once per block;
// each wave processes 4 rows SIMULTANEOUSLY (4x load ILP, ge reads amortized 4x);
// reduce chains pipelined; top-2/sigmoid tail runs in lanes 0-3 in parallel.
// Also converts x -> bf16 xb on the fly.
__global__ __launch_bounds__(256) void gating_kernel(
    const float* __restrict__ x,
    const float* __restrict__ gate_w,    // [1024][8] fp32 (original layout)
    const float* __restrict__ gate_b,
    int* __restrict__ rinfo_e, float* __restrict__ rinfo_w,
    int* __restrict__ bhist,
    unsigned short* __restrict__ xb) {   // nullable
  __shared__ float lgw[EE * 1028];       // [e][d], stride 1028 (16B-aligned, bank-spread)
  __shared__ int hist[EE];
  int tid = threadIdx.x;
  if (tid < EE) hist[tid] = 0;
  // stage gate_w -> lgw (coalesced 16B loads; writes ~2-way conflict max)
#pragma unroll
  for (int it = 0; it < 8; it++) {
    int k = tid + it * 256;              // float4 index over gate_w (2048 total)
    float4 g4 = ((const float4*)gate_w)[k];
    int d = k >> 1, eb = (k & 1) * 4;
    lgw[(eb + 0) * 1028 + d] = g4.x;
    lgw[(eb + 1) * 1028 + d] = g4.y;
    lgw[(eb + 2) * 1028 + d] = g4.z;
    lgw[(eb + 3) * 1028 + d] = g4.w;
  }
  __syncthreads();
  int lane = tid & 63, wv = tid >> 6;
  int p0 = lane & 1, p1 = (lane >> 1) & 1, p2 = (lane >> 2) & 1;
  int row0 = blockIdx.x * GR + wv * 4;   // this wave's 4 rows
  float acc[4][EE];
#pragma unroll
  for (int rr = 0; rr < 4; rr++)
#pragma unroll
    for (int e = 0; e < EE; e++) acc[rr][e] = 0.f;
#pragma unroll
  for (int i = 0; i < 4; i++) {
    int d4 = lane + i * 64;              // float4 index within row
    float4 ge[EE];
#pragma unroll
    for (int e = 0; e < EE; e++)
      ge[e] = *(const float4*)&lgw[e * 1028 + d4 * 4];   // conflict-free b128
#pragma unroll
    for (int rr = 0; rr < 4; rr++) {
      float4 xv = ((const float4*)(x + (size_t)(row0 + rr) * DD))[d4];
      if (xb) {
        uint2 st; st.x = pack2(xv.x, xv.y); st.y = pack2(xv.z, xv.w);
        *(uint2*)(xb + (size_t)(row0 + rr) * DD + (size_t)d4 * 4) = st;
      }
#pragma unroll
      for (int e = 0; e < EE; e++)
        acc[rr][e] += xv.x * ge[e].x + xv.y * ge[e].y + xv.z * ge[e].z + xv.w * ge[e].w;
    }
  }
  // reduce-scatter per row (4 independent chains, pipelined):
  // 8->4->2->1 halving then 3-stage butterfly; lane ends with full sum for
  // expert e(lane) = ((lane&1)<<2) | (lane&2) | ((lane>>2)&1).
  float v1[4];
#pragma unroll
  for (int rr = 0; rr < 4; rr++) {
    float v4[4];
#pragma unroll
    for (int k = 0; k < 4; k++) {
      float send = p0 ? acc[rr][k] : acc[rr][k + 4];
      float recv = __shfl_xor(send, 1, 64);
      v4[k] = (p0 ? acc[rr][k + 4] : acc[rr][k]) + recv;
    }
    float v2[2];
#pragma unroll
    for (int k = 0; k < 2; k++) {
      float send = p1 ? v4[k] : v4[k + 2];
      float recv = __shfl_xor(send, 2, 64);
      v2[k] = (p1 ? v4[k + 2] : v4[k]) + recv;
    }
    float send = p2 ? v2[0] : v2[1];
    float recv = __shfl_xor(send, 4, 64);
    float v = (p2 ? v2[1] : v2[0]) + recv;
    v += __shfl_xor(v, 8, 64);
    v += __shfl_xor(v, 16, 64);
    v += __shfl_xor(v, 32, 64);
    v1[rr] = v;
  }
  // gather: lane rr (rr<4) collects row rr's 8 logits (uniform-src broadcasts)
  float lg[EE];
#pragma unroll
  for (int e = 0; e < EE; e++) lg[e] = 0.f;
#pragma unroll
  for (int e = 0; e < EE; e++) {
    int src = ((e & 1) << 2) | (e & 2) | ((e >> 2) & 1);
#pragma unroll
    for (int rr = 0; rr < 4; rr++) {
      float tv = __shfl(v1[rr], src, 64);
      lg[e] = (lane == rr) ? tv : lg[e];
    }
  }
  // parallel tail: lanes 0..3 each finish one row
  if (lane < 4) {
    int row = row0 + lane;
#pragma unroll
    for (int e = 0; e < EE; e++) lg[e] += gate_b[e];
    int i1 = 0;
    for (int e = 1; e < EE; e++) if (lg[e] > lg[i1]) i1 = e;
    int i2 = (i1 == 0) ? 1 : 0;
    for (int e = 0; e < EE; e++) if (e != i1 && lg[e] > lg[i2]) i2 = e;
    float wA = 1.f / (1.f + __expf(lg[i2] - lg[i1]));  // p1/(p1+p2), arg <= 0
    float wB = 1.f - wA;
    rinfo_e[row] = i1 | (i2 << 8);
    rinfo_w[row * 2 + 0] = wA;
    rinfo_w[row * 2 + 1] = wB;
    atomicAdd(&hist[i1], 1);      // LDS atomics only
    atomicAdd(&hist[i2], 1);
  }
  __syncthreads();
  if (tid < EE) bhist[blockIdx.x * EE + tid] = hist[tid];
}

// ---------------- scan: totals, group offsets, per-block bases (deterministic) ----------------
__global__ __launch_bounds__(256) void scan_kernel(
    const int* __restrict__ bhist, int* __restrict__ cnt, int* __restrict__ bbase) {
  __shared__ int cs[32][EE];
  __shared__ int ofs[EE];
  int tid = threadIdx.x;
  int g = tid & 7, c = tid >> 3;   // 32 chunks of 32 blocks (GB=1024)
  int s = 0;
#pragma unroll 1
  for (int b = c * 32; b < c * 32 + 32; b++) s += bhist[b * EE + g];
  cs[c][g] = s;
  __syncthreads();
  if (tid == 0) {
    int run = 0;
    for (int gg = 0; gg < EE; gg++) {
      int tot = 0;
      for (int cc = 0; cc < 32; cc++) tot += cs[cc][gg];
      cnt[gg] = tot;
      cnt[32 + gg] = run;
      ofs[gg] = run;
      run += tot;
    }
  }
  __syncthreads();
  if (tid < EE) {
    int run = ofs[tid];
#pragma unroll 1
    for (int cc = 0; cc < 32; cc++) { int t = cs[cc][tid]; cs[cc][tid] = run; run += t; }
  }
  __syncthreads();
  int run = cs[c][g];
#pragma unroll 1
  for (int b = c * 32; b < c * 32 + 32; b++) {
    bbase[b * EE + g] = run;
    run += bhist[b * EE + g];
  }
}

// ---------------- scatter (also writes inverse map row -> (p0,p1)) ----------------
// NOTE: posmap may alias rinfo_w; reads of rinfo_w happen before posmap writes in-thread.
__global__ __launch_bounds__(64) void scatter_kernel(
    const int* __restrict__ rinfo_e, const float* rinfo_w,
    const int* __restrict__ bbase,
    int* __restrict__ rowidx, float* __restrict__ wgt, int* posmap) {
  __shared__ int curs[EE];
  int tid = threadIdx.x;
  if (tid < EE) curs[tid] = bbase[blockIdx.x * EE + tid];
  __syncthreads();
  if (tid < GR) {
    int row = blockIdx.x * GR + tid;
    int ee = rinfo_e[row];
    int e0 = ee & 255, e1 = (ee >> 8) & 255;
    float w0 = rinfo_w[row * 2 + 0];
    float w1 = rinfo_w[row * 2 + 1];
    int p0 = atomicAdd(&curs[e0], 1);
    rowidx[p0] = row; wgt[p0] = w0;
    int p1 = atomicAdd(&curs[e1], 1);
    rowidx[p1] = row; wgt[p1] = w1;
    posmap[row * 2 + 0] = p0;
    posmap[row * 2 + 1] = p1;
  }
}

// src fp32 [E][R][C] -> dst bf16 [E][C][R]
__global__ void transpose_kernel(const float* __restrict__ src,
                                 unsigned short* __restrict__ dst, int R, int C) {
  __shared__ float tbuf[32][33];
  int e = blockIdx.z;
  int c0 = blockIdx.x * 32, r0 = blockIdx.y * 32;
  int tx = threadIdx.x, ty = threadIdx.y;
  const float* s = src + (size_t)e * R * C;
  unsigned short* d = dst + (size_t)e * R * C;
  for (int yy = ty; yy < 32; yy += 8)
    tbuf[yy][tx] = s[(size_t)(r0 + yy) * C + c0 + tx];
  __syncthreads();
  for (int yy = ty; yy < 32; yy += 8)
    d[(size_t)(c0 + yy) * R + r0 + tx] = f2bf(tbuf[tx][yy]);
}

// ---------------- grouped GEMM1: h = gelu(Xg @ w1[e] + b1[e]) ----------------
// 128(M)x64(N) tile, grid (264,4) = 1056 blocks -> ~4 blocks/CU (16 waves/CU):
// latency hidden by cross-block TLP (m97/m114 regime). Single-buffered 24KB LDS.
// XOR chunk-swizzle: pre-swizzled global source -> linear global_load_lds dst ->
// XOR'd ds_read (verified conflict-free, round 3). 4 waves split along M (32 rows each).
// MFMA operands swapped (mfma(b,a) -> D^T): packed 8B epilogue stores.
template <bool ASYNC_A>
__global__ __launch_bounds__(256) void gemm1_kernel(
    const unsigned short* __restrict__ xb,    // bf16 [B][D] (ASYNC_A)
    const float* __restrict__ x,              // fp32 [B][D] (!ASYNC_A)
    const unsigned short* __restrict__ w1t,   // [E][H][D] bf16
    const float* __restrict__ b1,             // [E][H] fp32
    const int* __restrict__ cnt,
    const int* __restrict__ rowidx,
    unsigned short* __restrict__ hbuf,        // [32768][256] bf16 (packed by pos)
    int g0, int g1) {
  __shared__ unsigned short As[128 * 64];   // 16 KB
  __shared__ unsigned short Bs[64 * 64];    // 8 KB
  int t = blockIdx.x, g = -1, lt = 0;
#pragma unroll 1
  for (int gg = g0; gg < g1; gg++) {
    int nt = (cnt[gg] + 127) >> 7;
    if (t < nt) { g = gg; lt = t; break; }
    t -= nt;
  }
  if (g < 0) return;
  const int* offs = cnt + 32;
  int hb = offs[g0];
  int m0 = offs[g] + lt * 128;
  int mEnd = offs[g] + cnt[g];
  int e = g;
  int n0 = blockIdx.y * 64;
  const unsigned short* Bsrc = w1t + (size_t)e * HH * DD + (size_t)n0 * DD;
  int tid = threadIdx.x, lane = tid & 63, wv = tid >> 6;
  int wr = wv * 32;                      // wave's 32 output rows
  int lm = lane & 15, q = lane >> 4;
  int lm7 = lm & 7;
  floatx4 acc[2][4];
  floatx4 zero = {0.f, 0.f, 0.f, 0.f};
#pragma unroll
  for (int i = 0; i < 2; i++)
#pragma unroll
    for (int j = 0; j < 4; j++) acc[i][j] = zero;
  int srow = tid >> 3;                         // 0..31
  int ssrc = (((tid & 7) ^ (srow & 7))) * 8;   // swizzled source chunk (elems)
  int sdst = (tid & 7) * 8;                    // linear LDS slot (fp32 path)
  const unsigned short* gA[4];
  const float* gAf[4];
  const unsigned short* gBp[2];
#pragma unroll
  for (int i = 0; i < 4; i++) {
    int pos = m0 + i * 32 + srow;
    int grow = rowidx[pos < mEnd ? pos : m0];  // clamp: data discarded at epilogue
    if (ASYNC_A) gA[i] = xb + (size_t)grow * DD + ssrc;
    else         gAf[i] = x + (size_t)grow * DD + ssrc;
  }
#pragma unroll
  for (int i = 0; i < 2; i++)
    gBp[i] = Bsrc + (size_t)(i * 32 + srow) * DD + ssrc;
#pragma unroll 1
  for (int k0 = 0; k0 < DD; k0 += 64) {
    if (ASYNC_A) {
#pragma unroll
      for (int i = 0; i < 4; i++) async16(gA[i], &As[wv * 512 + i * 2048]);
#pragma unroll
      for (int i = 0; i < 4; i++) gA[i] += 64;
    } else {
#pragma unroll
      for (int i = 0; i < 4; i++) {
        float4 f0 = *(const float4*)gAf[i];
        float4 f1 = *(const float4*)(gAf[i] + 4);
        gAf[i] += 64;
        uint4 av;
        av.x = pack2(f0.x, f0.y); av.y = pack2(f0.z, f0.w);
        av.z = pack2(f1.x, f1.y); av.w = pack2(f1.z, f1.w);
        *(uint4*)&As[(i * 32 + srow) * 64 + sdst] = av;  // src swizzled, slot linear
      }
    }
#pragma unroll
    for (int i = 0; i < 2; i++) async16(gBp[i], &Bs[wv * 512 + i * 2048]);
#pragma unroll
    for (int i = 0; i < 2; i++) gBp[i] += 64;
    __syncthreads();
#pragma unroll
    for (int ks = 0; ks < 2; ks++) {
      short8 a[2], b[4];
#pragma unroll
      for (int i = 0; i < 2; i++)
        a[i] = *(const short8*)&As[(wr + i * 16 + lm) * 64 + ((ks * 4 + q) ^ lm7) * 8];
#pragma unroll
      for (int j = 0; j < 4; j++)
        b[j] = *(const short8*)&Bs[(j * 16 + lm) * 64 + ((ks * 4 + q) ^ lm7) * 8];
#pragma unroll
      for (int i = 0; i < 2; i++)
#pragma unroll
        for (int j = 0; j < 4; j++)
          acc[i][j] = __builtin_amdgcn_mfma_f32_16x16x32_bf16(b[j], a[i], acc[i][j], 0, 0, 0);
    }
    __syncthreads();
  }
  // D^T mapping: row m = wr+i*16+lm ; cols n = n0 + j*16 + q*4 + {0..3}
#pragma unroll
  for (int i = 0; i < 2; i++) {
    int pos = m0 + wr + i * 16 + lm;
    if (pos < mEnd) {
#pragma unroll
      for (int j = 0; j < 4; j++) {
        int col = n0 + j * 16 + q * 4;
        const float4 bb = *(const float4*)(b1 + e * HH + col);
        float v0 = acc[i][j][0] + bb.x;
        float v1 = acc[i][j][1] + bb.y;
        float v2 = acc[i][j][2] + bb.z;
        float v3 = acc[i][j][3] + bb.w;
        v0 = 0.5f * v0 * (1.f + erff(v0 * 0.70710678118654752f));  // exact GELU
        v1 = 0.5f * v1 * (1.f + erff(v1 * 0.70710678118654752f));
        v2 = 0.5f * v2 * (1.f + erff(v2 * 0.70710678118654752f));
        v3 = 0.5f * v3 * (1.f + erff(v3 * 0.70710678118654752f));
        uint2 st; st.x = pack2(v0, v1); st.y = pack2(v2, v3);
        *(uint2*)(hbuf + (size_t)(pos - hb) * HH + col) = st;
      }
    }
  }
}

// ---------------- grouped GEMM2: eo[pos] = bf16( w[pos] * (h @ w2[e] + b2[e]) ) ----------------
// Single-buffered (grid 2112 blocks -> TLP-rich; 64KB LDS would halve residency, m132).
// XOR chunk-swizzle on staging source + ds_read side.
// EO=true : packed bf16 rows to eo (no scatter, no RMW); combine_kernel finishes.
// EO=false: fallback, fp32 atomicAdd into zero-initialized out (2 commutative adds/elem).
template <bool EO>
__global__ __launch_bounds__(256) void gemm2_kernel(
    const unsigned short* __restrict__ hbuf,
    const unsigned short* __restrict__ w2t,   // [E][D][H] bf16
    const float* __restrict__ b2,             // [E][D] fp32
    const int* __restrict__ cnt,
    const int* __restrict__ rowidx,
    const float* __restrict__ wgt,
    unsigned short* __restrict__ eo,          // [32768][1024] bf16 (EO)
    float* out,                               // [B][D] fp32 (!EO)
    int g0, int g1) {
  __shared__ unsigned short As[128 * 64];
  __shared__ unsigned short Bs[128 * 64];
  int t = blockIdx.x, g = -1, lt = 0;
#pragma unroll 1
  for (int gg = g0; gg < g1; gg++) {
    int nt = (cnt[gg] + 127) >> 7;
    if (t < nt) { g = gg; lt = t; break; }
    t -= nt;
  }
  if (g < 0) return;
  const int* offs = cnt + 32;
  int hb = offs[g0];
  int m0 = offs[g] + lt * 128;
  int mEnd = offs[g] + cnt[g];
  int e = g;
  int n0 = blockIdx.y * 128;
  const unsigned short* Bsrc = w2t + (size_t)e * DD * HH + (size_t)n0 * HH;
  int tid = threadIdx.x, lane = tid & 63, wv = tid >> 6;
  int wr = (wv >> 1) * 64, wc = (wv & 1) * 64;
  int lm = lane & 15, q = lane >> 4;
  int lm7 = lm & 7;
  floatx4 acc[4][4];
  floatx4 zero = {0.f, 0.f, 0.f, 0.f};
#pragma unroll
  for (int i = 0; i < 4; i++)
#pragma unroll
    for (int j = 0; j < 4; j++) acc[i][j] = zero;
  int srow = tid >> 3;
  int ssrc = (((tid & 7) ^ (srow & 7))) * 8;   // swizzled source chunk
  const unsigned short* gA[4];
  const unsigned short* gBp[4];
#pragma unroll
  for (int i = 0; i < 4; i++) {
    int pos = m0 + i * 32 + srow;
    int posc = (pos < mEnd) ? pos : m0;       // clamp: discarded at epilogue
    gA[i] = hbuf + (size_t)(posc - hb) * HH + ssrc;
    gBp[i] = Bsrc + (size_t)(i * 32 + srow) * HH + ssrc;
  }
  unsigned short* AsW = As + wv * 512;
  unsigned short* BsW = Bs + wv * 512;
#pragma unroll 1
  for (int k0 = 0; k0 < HH; k0 += 64) {
#pragma unroll
    for (int i = 0; i < 4; i++) async16(gA[i], AsW + i * 2048);
#pragma unroll
    for (int i = 0; i < 4; i++) async16(gBp[i], BsW + i * 2048);
#pragma unroll
    for (int i = 0; i < 4; i++) { gA[i] += 64; gBp[i] += 64; }
    __syncthreads();
#pragma unroll
    for (int ks = 0; ks < 2; ks++) {
      short8 a[4], b[4];
#pragma unroll
      for (int i = 0; i < 4; i++)
        a[i] = *(const short8*)&As[(wr + i * 16 + lm) * 64 + ((ks * 4 + q) ^ lm7) * 8];
#pragma unroll
      for (int j = 0; j < 4; j++)
        b[j] = *(const short8*)&Bs[(wc + j * 16 + lm) * 64 + ((ks * 4 + q) ^ lm7) * 8];
#pragma unroll
      for (int i = 0; i < 4; i++)
#pragma unroll
        for (int j = 0; j < 4; j++)
          acc[i][j] = __builtin_amdgcn_mfma_f32_16x16x32_bf16(b[j], a[i], acc[i][j], 0, 0, 0);
    }
    __syncthreads();
  }
  // D^T mapping: row m = wr+i*16+lm ; cols n = wc + j*16 + q*4 + {0..3}
#pragma unroll
  for (int i = 0; i < 4; i++) {
    int pos = m0 + wr + i * 16 + lm;
    if (pos < mEnd) {
      float wrow = wgt[pos];
      if (EO) {
#pragma unroll
        for (int j = 0; j < 4; j++) {
          int col = n0 + wc + j * 16 + q * 4;
          const float4 bb = *(const float4*)(b2 + e * DD + col);
          uint2 st;
          st.x = pack2((acc[i][j][0] + bb.x) * wrow, (acc[i][j][1] + bb.y) * wrow);
          st.y = pack2((acc[i][j][2] + bb.z) * wrow, (acc[i][j][3] + bb.w) * wrow);
          *(uint2*)(eo + (size_t)pos * DD + col) = st;
        }
      } else {
        int grow = rowidx[pos];
#pragma unroll
        for (int j = 0; j < 4; j++) {
          int col = n0 + wc + j * 16 + q * 4;
          const float4 bb = *(const float4*)(b2 + e * DD + col);
          float* op = out + (size_t)grow * DD + col;
          atomicAdd(op + 0, (acc[i][j][0] + bb.x) * wrow);
          atomicAdd(op + 1, (acc[i][j][1] + bb.y) * wrow);
          atomicAdd(op + 2, (acc[i][j][2] + bb.z) * wrow);
          atomicAdd(op + 3, (acc[i][j][3] + bb.w) * wrow);
        }
      }
    }
  }
}

// ---------------- combine: out[row] = eo[p0] + eo[p1] (weights pre-applied) ----------------
__global__ __launch_bounds__(256) void combine_kernel(
    const unsigned short* __restrict__ eo, const int* __restrict__ posmap,
    float* __restrict__ out) {
  int row = blockIdx.x * 2 + (threadIdx.x >> 7);
  int t = threadIdx.x & 127;
  int p0 = posmap[row * 2 + 0];
  int p1 = posmap[row * 2 + 1];
  uint4 av = *((const uint4*)(eo + (size_t)p0 * DD) + t);
  uint4 bv = *((const uint4*)(eo + (size_t)p1 * DD) + t);
  unsigned int ua[4] = {av.x, av.y, av.z, av.w};
  unsigned int ub[4] = {bv.x, bv.y, bv.z, bv.w};
  float o[8];
#pragma unroll
  for (int k = 0; k < 4; k++) {
    o[2 * k]     = bf2f(ua[k] & 0xffffu) + bf2f(ub[k] & 0xffffu);
    o[2 * k + 1] = bf2f(ua[k] >> 16)     + bf2f(ub[k] >> 16);
  }
  float* op = out + (size_t)row * DD + t * 8;
  *(float4*)(op)     = make_float4(o[0], o[1], o[2], o[3]);
  *(float4*)(op + 4) = make_float4(o[4], o[5], o[6], o[7]);
}

extern "C" void kernel_launch(void* const* d_in, const int* in_sizes, int n_in,
                              void* d_out, int out_size, void* d_ws, size_t ws_size,
                              hipStream_t stream) {
  (void)in_sizes; (void)n_in; (void)out_size;
  const float* x      = (const float*)d_in[0];
  const float* gate_w = (const float*)d_in[1];
  const float* gate_b = (const float*)d_in[2];
  const float* w1     = (const float*)d_in[3];
  const float* b1     = (const float*)d_in[4];
  const float* w2     = (const float*)d_in[5];
  const float* b2     = (const float*)d_in[6];
  float* out = (float*)d_out;

  char* w = (char*)d_ws;
  int* cnt            = (int*)(w);                 // 48 ints (cnt[0..7], offs at +32)
  int* rinfo_e        = (int*)(w + 256);           // [16384]
  float* rinfo_w      = (float*)(w + 65792);       // [32768]
  int* posmap         = (int*)(w + 65792);         // aliases rinfo_w (safe: in-thread RAW order)
  int* bhist          = (int*)(w + 196864);        // [1024][8]
  int* bbase          = (int*)(w + 229632);        // [1024][8]
  int* rowidx         = (int*)(w + 262400);        // [32768]
  float* wgt          = (float*)(w + 393472);      // [32768]
  unsigned short* w1t = (unsigned short*)(w + 524544);   // 4 MB bf16
  unsigned short* w2t = (unsigned short*)(w + 4718848);  // 4 MB bf16
  unsigned short* hbuf= (unsigned short*)(w + 8913152);  // 16 MB bf16 [32768][256]
  unsigned short* xb  = (unsigned short*)(w + 25690368); // 32 MB bf16
  unsigned short* eo  = (unsigned short*)(w + 59244800); // 64 MB bf16 [32768][1024]
  bool use_xb = ws_size >= (size_t)59244800;
  bool use_eo = ws_size >= (size_t)126353664;

  transpose_kernel<<<dim3(HH / 32, DD / 32, EE), dim3(32, 8), 0, stream>>>(w1, w1t, DD, HH);
  transpose_kernel<<<dim3(DD / 32, HH / 32, EE), dim3(32, 8), 0, stream>>>(w2, w2t, HH, DD);
  gating_kernel<<<GB, 256, 0, stream>>>(x, gate_w, gate_b, rinfo_e, rinfo_w, bhist,
                                        use_xb ? xb : (unsigned short*)nullptr);
  scan_kernel<<<1, 256, 0, stream>>>(bhist, cnt, bbase);
  scatter_kernel<<<GB, 64, 0, stream>>>(rinfo_e, rinfo_w, bbase, rowidx, wgt, posmap);
  // m-tiles over 8 merged groups: sum(ceil(cnt_e/128)) <= 256+7 = 263 -> grid.x = 264
  if (use_eo) {
    gemm1_kernel<true><<<dim3(264, 4), 256, 0, stream>>>(xb, x, w1t, b1, cnt, rowidx, hbuf, 0, 8);
    gemm2_kernel<true><<<dim3(264, 8), 256, 0, stream>>>(hbuf, w2t, b2, cnt, rowidx, wgt, eo, nullptr, 0, 8);
    combine_kernel<<<BN / 2, 256, 0, stream>>>(eo, posmap, out);
  } else if (use_xb) {
    hipMemsetAsync(out, 0, (size_t)BN * DD * 4, stream);
    gemm1_kernel<true><<<dim3(264, 4), 256, 0, stream>>>(xb, x, w1t, b1, cnt, rowidx, hbuf, 0, 8);
    gemm2_kernel<false><<<dim3(264, 8), 256, 0, stream>>>(hbuf, w2t, b2, cnt, rowidx, wgt, nullptr, out, 0, 8);
  } else {
    hipMemsetAsync(out, 0, (size_t)BN * DD * 4, stream);
    gemm1_kernel<false><<<dim3(264, 4), 256, 0, stream>>>(nullptr, x, w1t, b1, cnt, rowidx, hbuf, 0, 8);
    gemm2_kernel<false><<<dim3(264, 8), 256, 0, stream>>>(hbuf, w2t, b2, cnt, rowidx, wgt, nullptr, out, 0, 8);
  }
}

// Round 8
// 275.803 us; speedup vs baseline: 1.0403x; 1.0004x over previous
//
#include <hip/hip_runtime.h>
#include <stdint.h>

#define BN 16384
#define DD 1024
#define HH 256
#define EE 8
#define GB 1024  // gating blocks
#define GR 16    // rows per gating block

typedef __attribute__((ext_vector_type(8))) short short8;
typedef __attribute__((ext_vector_type(4))) float floatx4;

__device__ __forceinline__ unsigned short f2bf(float f) {
  union { float f; unsigned int i; } v; v.f = f;
  unsigned int x = v.i;
  x += 0x7fffu + ((x >> 16) & 1u);  // RTNE
  return (unsigned short)(x >> 16);
}
__device__ __forceinline__ unsigned int pack2(float a, float b) {
  return (unsigned int)f2bf(a) | ((unsigned int)f2bf(b) << 16);
}
__device__ __forceinline__ float bf2f(unsigned int u16) {
  union { unsigned int i; float f; } v; v.i = u16 << 16; return v.f;
}
// async 16B/lane global->LDS DMA; lds dst must be wave-uniform base (+lane*16 by HW)
__device__ __forceinline__ void async16(const unsigned short* g, unsigned short* l) {
  __builtin_amdgcn_global_load_lds(
      (const __attribute__((address_space(1))) void*)g,
      (__attribute__((address_space(3))) void*)l, 16, 0, 0);
}

// ---------------- gating: fp32 logits -> top2 -> rinfo + per-block histogram ----------------
// gate_w staged to LDS (transposed, padded stride) once per block; each wave processes
// 4 rows simultaneously; reduce chains pipelined; tail in lanes 0-3. Converts x->xb.
__global__ __launch_bounds__(256) void gating_kernel(
    const float* __restrict__ x,
    const float* __restrict__ gate_w,    // [1024][8] fp32 (original layout)
    const float* __restrict__ gate_b,
    int* __restrict__ rinfo_e, float* __restrict__ rinfo_w,
    int* __restrict__ bhist,
    unsigned short* __restrict__ xb) {   // nullable
  __shared__ float lgw[EE * 1028];       // [e][d], stride 1028 (16B-aligned, bank-spread)
  __shared__ int hist[EE];
  int tid = threadIdx.x;
  if (tid < EE) hist[tid] = 0;
  // stage gate_w -> lgw (coalesced 16B loads; writes ~2-way conflict max)
#pragma unroll
  for (int it = 0; it < 8; it++) {
    int k = tid + it * 256;              // float4 index over gate_w (2048 total)
    float4 g4 = ((const float4*)gate_w)[k];
    int d = k >> 1, eb = (k & 1) * 4;
    lgw[(eb + 0) * 1028 + d] = g4.x;
    lgw[(eb + 1) * 1028 + d] = g4.y;
    lgw[(eb + 2) * 1028 + d] = g4.z;
    lgw[(eb + 3) * 1028 + d] = g4.w;
  }
  __syncthreads();
  int lane = tid & 63, wv = tid >> 6;
  int p0 = lane & 1, p1 = (lane >> 1) & 1, p2 = (lane >> 2) & 1;
  int row0 = blockIdx.x * GR + wv * 4;   // this wave's 4 rows
  float acc[4][EE];
#pragma unroll
  for (int rr = 0; rr < 4; rr++)
#pragma unroll
    for (int e = 0; e < EE; e++) acc[rr][e] = 0.f;
#pragma unroll
  for (int i = 0; i < 4; i++) {
    int d4 = lane + i * 64;              // float4 index within row
    float4 ge[EE];
#pragma unroll
    for (int e = 0; e < EE; e++)
      ge[e] = *(const float4*)&lgw[e * 1028 + d4 * 4];   // conflict-free b128
#pragma unroll
    for (int rr = 0; rr < 4; rr++) {
      float4 xv = ((const float4*)(x + (size_t)(row0 + rr) * DD))[d4];
      if (xb) {
        uint2 st; st.x = pack2(xv.x, xv.y); st.y = pack2(xv.z, xv.w);
        *(uint2*)(xb + (size_t)(row0 + rr) * DD + (size_t)d4 * 4) = st;
      }
#pragma unroll
      for (int e = 0; e < EE; e++)
        acc[rr][e] += xv.x * ge[e].x + xv.y * ge[e].y + xv.z * ge[e].z + xv.w * ge[e].w;
    }
  }
  // reduce-scatter per row: 8->4->2->1 halving then 3-stage butterfly; lane ends with
  // full sum for expert e(lane) = ((lane&1)<<2) | (lane&2) | ((lane>>2)&1).
  float v1[4];
#pragma unroll
  for (int rr = 0; rr < 4; rr++) {
    float v4[4];
#pragma unroll
    for (int k = 0; k < 4; k++) {
      float send = p0 ? acc[rr][k] : acc[rr][k + 4];
      float recv = __shfl_xor(send, 1, 64);
      v4[k] = (p0 ? acc[rr][k + 4] : acc[rr][k]) + recv;
    }
    float v2[2];
#pragma unroll
    for (int k = 0; k < 2; k++) {
      float send = p1 ? v4[k] : v4[k + 2];
      float recv = __shfl_xor(send, 2, 64);
      v2[k] = (p1 ? v4[k + 2] : v4[k]) + recv;
    }
    float send = p2 ? v2[0] : v2[1];
    float recv = __shfl_xor(send, 4, 64);
    float v = (p2 ? v2[1] : v2[0]) + recv;
    v += __shfl_xor(v, 8, 64);
    v += __shfl_xor(v, 16, 64);
    v += __shfl_xor(v, 32, 64);
    v1[rr] = v;
  }
  // gather: lane rr (rr<4) collects row rr's 8 logits (uniform-src broadcasts)
  float lg[EE];
#pragma unroll
  for (int e = 0; e < EE; e++) lg[e] = 0.f;
#pragma unroll
  for (int e = 0; e < EE; e++) {
    int src = ((e & 1) << 2) | (e & 2) | ((e >> 2) & 1);
#pragma unroll
    for (int rr = 0; rr < 4; rr++) {
      float tv = __shfl(v1[rr], src, 64);
      lg[e] = (lane == rr) ? tv : lg[e];
    }
  }
  // parallel tail: lanes 0..3 each finish one row
  if (lane < 4) {
    int row = row0 + lane;
#pragma unroll
    for (int e = 0; e < EE; e++) lg[e] += gate_b[e];
    int i1 = 0;
    for (int e = 1; e < EE; e++) if (lg[e] > lg[i1]) i1 = e;
    int i2 = (i1 == 0) ? 1 : 0;
    for (int e = 0; e < EE; e++) if (e != i1 && lg[e] > lg[i2]) i2 = e;
    float wA = 1.f / (1.f + __expf(lg[i2] - lg[i1]));  // p1/(p1+p2), arg <= 0
    float wB = 1.f - wA;
    rinfo_e[row] = i1 | (i2 << 8);
    rinfo_w[row * 2 + 0] = wA;
    rinfo_w[row * 2 + 1] = wB;
    atomicAdd(&hist[i1], 1);      // LDS atomics only
    atomicAdd(&hist[i2], 1);
  }
  __syncthreads();
  if (tid < EE) bhist[blockIdx.x * EE + tid] = hist[tid];
}

// ---------------- scan: totals, group offsets, per-block bases (deterministic) ----------------
__global__ __launch_bounds__(256) void scan_kernel(
    const int* __restrict__ bhist, int* __restrict__ cnt, int* __restrict__ bbase) {
  __shared__ int cs[32][EE];
  __shared__ int ofs[EE];
  int tid = threadIdx.x;
  int g = tid & 7, c = tid >> 3;   // 32 chunks of 32 blocks (GB=1024)
  int s = 0;
#pragma unroll 1
  for (int b = c * 32; b < c * 32 + 32; b++) s += bhist[b * EE + g];
  cs[c][g] = s;
  __syncthreads();
  if (tid == 0) {
    int run = 0;
    for (int gg = 0; gg < EE; gg++) {
      int tot = 0;
      for (int cc = 0; cc < 32; cc++) tot += cs[cc][gg];
      cnt[gg] = tot;
      cnt[32 + gg] = run;
      ofs[gg] = run;
      run += tot;
    }
  }
  __syncthreads();
  if (tid < EE) {
    int run = ofs[tid];
#pragma unroll 1
    for (int cc = 0; cc < 32; cc++) { int t = cs[cc][tid]; cs[cc][tid] = run; run += t; }
  }
  __syncthreads();
  int run = cs[c][g];
#pragma unroll 1
  for (int b = c * 32; b < c * 32 + 32; b++) {
    bbase[b * EE + g] = run;
    run += bhist[b * EE + g];
  }
}

// ---------------- scatter (also writes inverse map row -> (p0,p1)) ----------------
// NOTE: posmap may alias rinfo_w; reads of rinfo_w happen before posmap writes in-thread.
__global__ __launch_bounds__(64) void scatter_kernel(
    const int* __restrict__ rinfo_e, const float* rinfo_w,
    const int* __restrict__ bbase,
    int* __restrict__ rowidx, float* __restrict__ wgt, int* posmap) {
  __shared__ int curs[EE];
  int tid = threadIdx.x;
  if (tid < EE) curs[tid] = bbase[blockIdx.x * EE + tid];
  __syncthreads();
  if (tid < GR) {
    int row = blockIdx.x * GR + tid;
    int ee = rinfo_e[row];
    int e0 = ee & 255, e1 = (ee >> 8) & 255;
    float w0 = rinfo_w[row * 2 + 0];
    float w1 = rinfo_w[row * 2 + 1];
    int p0 = atomicAdd(&curs[e0], 1);
    rowidx[p0] = row; wgt[p0] = w0;
    int p1 = atomicAdd(&curs[e1], 1);
    rowidx[p1] = row; wgt[p1] = w1;
    posmap[row * 2 + 0] = p0;
    posmap[row * 2 + 1] = p1;
  }
}

// src fp32 [E][R][C] -> dst bf16 [E][C][R]
__global__ void transpose_kernel(const float* __restrict__ src,
                                 unsigned short* __restrict__ dst, int R, int C) {
  __shared__ float tbuf[32][33];
  int e = blockIdx.z;
  int c0 = blockIdx.x * 32, r0 = blockIdx.y * 32;
  int tx = threadIdx.x, ty = threadIdx.y;
  const float* s = src + (size_t)e * R * C;
  unsigned short* d = dst + (size_t)e * R * C;
  for (int yy = ty; yy < 32; yy += 8)
    tbuf[yy][tx] = s[(size_t)(r0 + yy) * C + c0 + tx];
  __syncthreads();
  for (int yy = ty; yy < 32; yy += 8)
    d[(size_t)(c0 + yy) * R + r0 + tx] = f2bf(tbuf[tx][yy]);
}

// ---------------- grouped GEMM1: h = gelu(Xg @ w1[e] + b1[e]) ----------------
// 128(M)x64(N) tile, grid (264,4). XCD-locality remap: bid=(x+264*y); a=bid&7
// selects the XCD (round-robin dispatch); m-tile = a*33 + (bid>>3)%33, n = (bid>>3)/33.
// All 4 N-blocks of an m-panel land on the SAME XCD -> A-panel re-reads hit private L2
// (~200cy) instead of L3. Bijective since 264 = 8*33. Single-buffered 24KB LDS;
// XOR chunk-swizzle (conflict-free); mfma(b,a) -> D^T packed 8B epilogue stores.
template <bool ASYNC_A>
__global__ __launch_bounds__(256) void gemm1_kernel(
    const unsigned short* __restrict__ xb,    // bf16 [B][D] (ASYNC_A)
    const float* __restrict__ x,              // fp32 [B][D] (!ASYNC_A)
    const unsigned short* __restrict__ w1t,   // [E][H][D] bf16
    const float* __restrict__ b1,             // [E][H] fp32
    const int* __restrict__ cnt,
    const int* __restrict__ rowidx,
    unsigned short* __restrict__ hbuf,        // [32768][256] bf16 (packed by pos)
    int g0, int g1) {
  __shared__ unsigned short As[128 * 64];   // 16 KB
  __shared__ unsigned short Bs[64 * 64];    // 8 KB
  int bid = blockIdx.x + 264 * blockIdx.y;
  int xa = bid & 7, xb_ = bid >> 3;         // xb_ in [0,528)
  int t = xa * 33 + (xb_ % 33);             // m-tile index [0,264)
  int ny = xb_ / 33;                        // n-block [0,4)
  int g = -1, lt = 0;
#pragma unroll 1
  for (int gg = g0; gg < g1; gg++) {
    int nt = (cnt[gg] + 127) >> 7;
    if (t < nt) { g = gg; lt = t; break; }
    t -= nt;
  }
  if (g < 0) return;
  const int* offs = cnt + 32;
  int hb = offs[g0];
  int m0 = offs[g] + lt * 128;
  int mEnd = offs[g] + cnt[g];
  int e = g;
  int n0 = ny * 64;
  const unsigned short* Bsrc = w1t + (size_t)e * HH * DD + (size_t)n0 * DD;
  int tid = threadIdx.x, lane = tid & 63, wv = tid >> 6;
  int wr = wv * 32;                      // wave's 32 output rows
  int lm = lane & 15, q = lane >> 4;
  int lm7 = lm & 7;
  floatx4 acc[2][4];
  floatx4 zero = {0.f, 0.f, 0.f, 0.f};
#pragma unroll
  for (int i = 0; i < 2; i++)
#pragma unroll
    for (int j = 0; j < 4; j++) acc[i][j] = zero;
  int srow = tid >> 3;                         // 0..31
  int ssrc = (((tid & 7) ^ (srow & 7))) * 8;   // swizzled source chunk (elems)
  int sdst = (tid & 7) * 8;                    // linear LDS slot (fp32 path)
  const unsigned short* gA[4];
  const float* gAf[4];
  const unsigned short* gBp[2];
#pragma unroll
  for (int i = 0; i < 4; i++) {
    int pos = m0 + i * 32 + srow;
    int grow = rowidx[pos < mEnd ? pos : m0];  // clamp: data discarded at epilogue
    if (ASYNC_A) gA[i] = xb + (size_t)grow * DD + ssrc;
    else         gAf[i] = x + (size_t)grow * DD + ssrc;
  }
#pragma unroll
  for (int i = 0; i < 2; i++)
    gBp[i] = Bsrc + (size_t)(i * 32 + srow) * DD + ssrc;
#pragma unroll 1
  for (int k0 = 0; k0 < DD; k0 += 64) {
    if (ASYNC_A) {
#pragma unroll
      for (int i = 0; i < 4; i++) async16(gA[i], &As[wv * 512 + i * 2048]);
#pragma unroll
      for (int i = 0; i < 4; i++) gA[i] += 64;
    } else {
#pragma unroll
      for (int i = 0; i < 4; i++) {
        float4 f0 = *(const float4*)gAf[i];
        float4 f1 = *(const float4*)(gAf[i] + 4);
        gAf[i] += 64;
        uint4 av;
        av.x = pack2(f0.x, f0.y); av.y = pack2(f0.z, f0.w);
        av.z = pack2(f1.x, f1.y); av.w = pack2(f1.z, f1.w);
        *(uint4*)&As[(i * 32 + srow) * 64 + sdst] = av;  // src swizzled, slot linear
      }
    }
#pragma unroll
    for (int i = 0; i < 2; i++) async16(gBp[i], &Bs[wv * 512 + i * 2048]);
#pragma unroll
    for (int i = 0; i < 2; i++) gBp[i] += 64;
    __syncthreads();
#pragma unroll
    for (int ks = 0; ks < 2; ks++) {
      short8 a[2], b[4];
#pragma unroll
      for (int i = 0; i < 2; i++)
        a[i] = *(const short8*)&As[(wr + i * 16 + lm) * 64 + ((ks * 4 + q) ^ lm7) * 8];
#pragma unroll
      for (int j = 0; j < 4; j++)
        b[j] = *(const short8*)&Bs[(j * 16 + lm) * 64 + ((ks * 4 + q) ^ lm7) * 8];
#pragma unroll
      for (int i = 0; i < 2; i++)
#pragma unroll
        for (int j = 0; j < 4; j++)
          acc[i][j] = __builtin_amdgcn_mfma_f32_16x16x32_bf16(b[j], a[i], acc[i][j], 0, 0, 0);
    }
    __syncthreads();
  }
  // D^T mapping: row m = wr+i*16+lm ; cols n = n0 + j*16 + q*4 + {0..3}
#pragma unroll
  for (int i = 0; i < 2; i++) {
    int pos = m0 + wr + i * 16 + lm;
    if (pos < mEnd) {
#pragma unroll
      for (int j = 0; j < 4; j++) {
        int col = n0 + j * 16 + q * 4;
        const float4 bb = *(const float4*)(b1 + e * HH + col);
        float v0 = acc[i][j][0] + bb.x;
        float v1 = acc[i][j][1] + bb.y;
        float v2 = acc[i][j][2] + bb.z;
        float v3 = acc[i][j][3] + bb.w;
        v0 = 0.5f * v0 * (1.f + erff(v0 * 0.70710678118654752f));  // exact GELU
        v1 = 0.5f * v1 * (1.f + erff(v1 * 0.70710678118654752f));
        v2 = 0.5f * v2 * (1.f + erff(v2 * 0.70710678118654752f));
        v3 = 0.5f * v3 * (1.f + erff(v3 * 0.70710678118654752f));
        uint2 st; st.x = pack2(v0, v1); st.y = pack2(v2, v3);
        *(uint2*)(hbuf + (size_t)(pos - hb) * HH + col) = st;
      }
    }
  }
}

// ---------------- grouped GEMM2: eo[pos] = bf16( w[pos] * (h @ w2[e] + b2[e]) ) ----------------
// Single-buffered; XCD-locality remap (264=8*33, 8 N-blocks of an m-panel -> same XCD,
// hbuf A-panel read 8x from private L2). XOR chunk-swizzle on staging + ds_read.
// EO=true : packed bf16 rows to eo (no scatter, no RMW); combine_kernel finishes.
// EO=false: fallback, fp32 atomicAdd into zero-initialized out (2 commutative adds/elem).
template <bool EO>
__global__ __launch_bounds__(256) void gemm2_kernel(
    const unsigned short* __restrict__ hbuf,
    const unsigned short* __restrict__ w2t,   // [E][D][H] bf16
    const float* __restrict__ b2,             // [E][D] fp32
    const int* __restrict__ cnt,
    const int* __restrict__ rowidx,
    const float* __restrict__ wgt,
    unsigned short* __restrict__ eo,          // [32768][1024] bf16 (EO)
    float* out,                               // [B][D] fp32 (!EO)
    int g0, int g1) {
  __shared__ unsigned short As[128 * 64];
  __shared__ unsigned short Bs[128 * 64];
  int bid = blockIdx.x + 264 * blockIdx.y;
  int xa = bid & 7, xb_ = bid >> 3;         // xb_ in [0,1056)
  int t = xa * 33 + (xb_ % 33);             // m-tile index [0,264)
  int ny = xb_ / 33;                        // n-block [0,8)
  int g = -1, lt = 0;
#pragma unroll 1
  for (int gg = g0; gg < g1; gg++) {
    int nt = (cnt[gg] + 127) >> 7;
    if (t < nt) { g = gg; lt = t; break; }
    t -= nt;
  }
  if (g < 0) return;
  const int* offs = cnt + 32;
  int hb = offs[g0];
  int m0 = offs[g] + lt * 128;
  int mEnd = offs[g] + cnt[g];
  int e = g;
  int n0 = ny * 128;
  const unsigned short* Bsrc = w2t + (size_t)e * DD * HH + (size_t)n0 * HH;
  int tid = threadIdx.x, lane = tid & 63, wv = tid >> 6;
  int wr = (wv >> 1) * 64, wc = (wv & 1) * 64;
  int lm = lane & 15, q = lane >> 4;
  int lm7 = lm & 7;
  floatx4 acc[4][4];
  floatx4 zero = {0.f, 0.f, 0.f, 0.f};
#pragma unroll
  for (int i = 0; i < 4; i++)
#pragma unroll
    for (int j = 0; j < 4; j++) acc[i][j] = zero;
  int srow = tid >> 3;
  int ssrc = (((tid & 7) ^ (srow & 7))) * 8;   // swizzled source chunk
  const unsigned short* gA[4];
  const unsigned short* gBp[4];
#pragma unroll
  for (int i = 0; i < 4; i++) {
    int pos = m0 + i * 32 + srow;
    int posc = (pos < mEnd) ? pos : m0;       // clamp: discarded at epilogue
    gA[i] = hbuf + (size_t)(posc - hb) * HH + ssrc;
    gBp[i] = Bsrc + (size_t)(i * 32 + srow) * HH + ssrc;
  }
  unsigned short* AsW = As + wv * 512;
  unsigned short* BsW = Bs + wv * 512;
#pragma unroll 1
  for (int k0 = 0; k0 < HH; k0 += 64) {
#pragma unroll
    for (int i = 0; i < 4; i++) async16(gA[i], AsW + i * 2048);
#pragma unroll
    for (int i = 0; i < 4; i++) async16(gBp[i], BsW + i * 2048);
#pragma unroll
    for (int i = 0; i < 4; i++) { gA[i] += 64; gBp[i] += 64; }
    __syncthreads();
#pragma unroll
    for (int ks = 0; ks < 2; ks++) {
      short8 a[4], b[4];
#pragma unroll
      for (int i = 0; i < 4; i++)
        a[i] = *(const short8*)&As[(wr + i * 16 + lm) * 64 + ((ks * 4 + q) ^ lm7) * 8];
#pragma unroll
      for (int j = 0; j < 4; j++)
        b[j] = *(const short8*)&Bs[(wc + j * 16 + lm) * 64 + ((ks * 4 + q) ^ lm7) * 8];
#pragma unroll
      for (int i = 0; i < 4; i++)
#pragma unroll
        for (int j = 0; j < 4; j++)
          acc[i][j] = __builtin_amdgcn_mfma_f32_16x16x32_bf16(b[j], a[i], acc[i][j], 0, 0, 0);
    }
    __syncthreads();
  }
  // D^T mapping: row m = wr+i*16+lm ; cols n = wc + j*16 + q*4 + {0..3}
#pragma unroll
  for (int i = 0; i < 4; i++) {
    int pos = m0 + wr + i * 16 + lm;
    if (pos < mEnd) {
      float wrow = wgt[pos];
      if (EO) {
#pragma unroll
        for (int j = 0; j < 4; j++) {
          int col = n0 + wc + j * 16 + q * 4;
          const float4 bb = *(const float4*)(b2 + e * DD + col);
          uint2 st;
          st.x = pack2((acc[i][j][0] + bb.x) * wrow, (acc[i][j][1] + bb.y) * wrow);
          st.y = pack2((acc[i][j][2] + bb.z) * wrow, (acc[i][j][3] + bb.w) * wrow);
          *(uint2*)(eo + (size_t)pos * DD + col) = st;
        }
      } else {
        int grow = rowidx[pos];
#pragma unroll
        for (int j = 0; j < 4; j++) {
          int col = n0 + wc + j * 16 + q * 4;
          const float4 bb = *(const float4*)(b2 + e * DD + col);
          float* op = out + (size_t)grow * DD + col;
          atomicAdd(op + 0, (acc[i][j][0] + bb.x) * wrow);
          atomicAdd(op + 1, (acc[i][j][1] + bb.y) * wrow);
          atomicAdd(op + 2, (acc[i][j][2] + bb.z) * wrow);
          atomicAdd(op + 3, (acc[i][j][3] + bb.w) * wrow);
        }
      }
    }
  }
}

// ---------------- combine: out[row] = eo[p0] + eo[p1] (weights pre-applied) ----------------
__global__ __launch_bounds__(256) void combine_kernel(
    const unsigned short* __restrict__ eo, const int* __restrict__ posmap,
    float* __restrict__ out) {
  int row = blockIdx.x * 2 + (threadIdx.x >> 7);
  int t = threadIdx.x & 127;
  int p0 = posmap[row * 2 + 0];
  int p1 = posmap[row * 2 + 1];
  uint4 av = *((const uint4*)(eo + (size_t)p0 * DD) + t);
  uint4 bv = *((const uint4*)(eo + (size_t)p1 * DD) + t);
  unsigned int ua[4] = {av.x, av.y, av.z, av.w};
  unsigned int ub[4] = {bv.x, bv.y, bv.z, bv.w};
  float o[8];
#pragma unroll
  for (int k = 0; k < 4; k++) {
    o[2 * k]     = bf2f(ua[k] & 0xffffu) + bf2f(ub[k] & 0xffffu);
    o[2 * k + 1] = bf2f(ua[k] >> 16)     + bf2f(ub[k] >> 16);
  }
  float* op = out + (size_t)row * DD + t * 8;
  *(float4*)(op)     = make_float4(o[0], o[1], o[2], o[3]);
  *(float4*)(op + 4) = make_float4(o[4], o[5], o[6], o[7]);
}

extern "C" void kernel_launch(void* const* d_in, const int* in_sizes, int n_in,
                              void* d_out, int out_size, void* d_ws, size_t ws_size,
                              hipStream_t stream) {
  (void)in_sizes; (void)n_in; (void)out_size;
  const float* x      = (const float*)d_in[0];
  const float* gate_w = (const float*)d_in[1];
  const float* gate_b = (const float*)d_in[2];
  const float* w1     = (const float*)d_in[3];
  const float* b1     = (const float*)d_in[4];
  const float* w2     = (const float*)d_in[5];
  const float* b2     = (const float*)d_in[6];
  float* out = (float*)d_out;

  char* w = (char*)d_ws;
  int* cnt            = (int*)(w);                 // 48 ints (cnt[0..7], offs at +32)
  int* rinfo_e        = (int*)(w + 256);           // [16384]
  float* rinfo_w      = (float*)(w + 65792);       // [32768]
  int* posmap         = (int*)(w + 65792);         // aliases rinfo_w (safe: in-thread RAW order)
  int* bhist          = (int*)(w + 196864);        // [1024][8]
  int* bbase          = (int*)(w + 229632);        // [1024][8]
  int* rowidx         = (int*)(w + 262400);        // [32768]
  float* wgt          = (float*)(w + 393472);      // [32768]
  unsigned short* w1t = (unsigned short*)(w + 524544);   // 4 MB bf16
  unsigned short* w2t = (unsigned short*)(w + 4718848);  // 4 MB bf16
  unsigned short* hbuf= (unsigned short*)(w + 8913152);  // 16 MB bf16 [32768][256]
  unsigned short* xb  = (unsigned short*)(w + 25690368); // 32 MB bf16
  unsigned short* eo  = (unsigned short*)(w + 59244800); // 64 MB bf16 [32768][1024]
  bool use_xb = ws_size >= (size_t)59244800;
  bool use_eo = ws_size >= (size_t)126353664;

  transpose_kernel<<<dim3(HH / 32, DD / 32, EE), dim3(32, 8), 0, stream>>>(w1, w1t, DD, HH);
  transpose_kernel<<<dim3(DD / 32, HH / 32, EE), dim3(32, 8), 0, stream>>>(w2, w2t, HH, DD);
  gating_kernel<<<GB, 256, 0, stream>>>(x, gate_w, gate_b, rinfo_e, rinfo_w, bhist,
                                        use_xb ? xb : (unsigned short*)nullptr);
  scan_kernel<<<1, 256, 0, stream>>>(bhist, cnt, bbase);
  scatter_kernel<<<GB, 64, 0, stream>>>(rinfo_e, rinfo_w, bbase, rowidx, wgt, posmap);
  // m-tiles over 8 merged groups: sum(ceil(cnt_e/128)) <= 256+7 = 263 -> grid.x = 264
  if (use_eo) {
    gemm1_kernel<true><<<dim3(264, 4), 256, 0, stream>>>(xb, x, w1t, b1, cnt, rowidx, hbuf, 0, 8);
    gemm2_kernel<true><<<dim3(264, 8), 256, 0, stream>>>(hbuf, w2t, b2, cnt, rowidx, wgt, eo, nullptr, 0, 8);
    combine_kernel<<<BN / 2, 256, 0, stream>>>(eo, posmap, out);
  } else if (use_xb) {
    hipMemsetAsync(out, 0, (size_t)BN * DD * 4, stream);
    gemm1_kernel<true><<<dim3(264, 4), 256, 0, stream>>>(xb, x, w1t, b1, cnt, rowidx, hbuf, 0, 8);
    gemm2_kernel<false><<<dim3(264, 8), 256, 0, stream>>>(hbuf, w2t, b2, cnt, rowidx, wgt, nullptr, out, 0, 8);
  } else {
    hipMemsetAsync(out, 0, (size_t)BN * DD * 4, stream);
    gemm1_kernel<false><<<dim3(264, 4), 256, 0, stream>>>(nullptr, x, w1t, b1, cnt, rowidx, hbuf, 0, 8);
    gemm2_kernel<false><<<dim3(264, 8), 256, 0, stream>>>(hbuf, w2t, b2, cnt, rowidx, wgt, nullptr, out, 0, 8);
  }
}